// Round 10
// baseline (1827.779 us; speedup 1.0000x reference)
//
#include <hip/hip_runtime.h>
#include <cstddef>
#include <cstdint>

#define BB   512
#define TT   128
#define DD   512
#define HH   4
#define HDIM 128
#define FFD  2048
#define NROWS (BB * TT)                 // 65536 rows
#define SLOT ((size_t)NROWS * DD)       // 33554432 floats = 128 MiB

typedef unsigned short u16;
typedef __bf16 bf16x8 __attribute__((ext_vector_type(8)));
typedef float  f32x4  __attribute__((ext_vector_type(4)));

__device__ __forceinline__ u16 f2b(float x) {
    union { float f; unsigned u; } v; v.f = x;
    unsigned r = v.u + 0x7FFFu + ((v.u >> 16) & 1u);
    return (u16)(r >> 16);
}
__device__ __forceinline__ float b2f(u16 u) {
    union { unsigned u; float f; } v; v.u = (unsigned)u << 16; return v.f;
}
__device__ __forceinline__ float fast_gelu(float v) {
    float t = v * (0.7978845608028654f + 0.0356774081f * v * v);
    float e = __expf(2.f * t);
    float th = 1.f - 2.f / (e + 1.f);          // tanh(t)
    return 0.5f * v * (1.f + th);
}
__device__ __forceinline__ void glds16(const void* g, void* l) {
    __builtin_amdgcn_global_load_lds(
        (const __attribute__((address_space(1))) void*)g,
        (__attribute__((address_space(3))) void*)l, 16, 0, 0);
}

// ============ 128x128 bf16 GEMM, BK=32, single-buffer (R4-best) =============
// stage (4 glds/thread) -> __syncthreads -> 16 MFMA/wave -> __syncthreads.
// LDS 16 KiB (32 KiB for MODE 7 epilogue scratch). Chunk swizzle:
// phys chunk p: row=p>>2, holds logical k-chunk (p&3)^(row&3)  (4-way max).
// MODE 2: bf16 out = addsrc_bf16[r*M+c] + 0.3*C. MODE 3: bf16 gelu(C).
// MODE 4: bf16 C. MODE 6: gate/delta interleave -> sigmoid*tanh @ c>>1.
// MODE 7: qkv -> cols<1024 bf16 (ld 1024); cols>=1024 V^T swizzled tiles.
template<int MODE>
__global__ __launch_bounds__(256)
void gemm128(const u16* __restrict__ A, const u16* __restrict__ BT,
             const float* __restrict__ bias, void* __restrict__ Cout, int ldc,
             const void* __restrict__ addsrc, void* __restrict__ aux,
             int K, int M)
{
    __shared__ u16 S[(MODE == 7) ? 16384 : 8192];
    const int tid = threadIdx.x;
    const int gx  = gridDim.x;
    const int nwg = gx * gridDim.y;
    int orig = blockIdx.y * gx + blockIdx.x;
    if ((nwg & 7) == 0) orig = (orig & 7) * (nwg >> 3) + (orig >> 3);
    const int row0 = (orig / gx) * 128;
    const int col0 = (orig % gx) * 128;

    const int lane = tid & 63;
    const int w    = tid >> 6;
    const int wr   = (w >> 1) * 64;
    const int wc   = (w & 1) * 64;
    const int fr   = lane & 15;
    const int kq   = lane >> 4;

    f32x4 acc[4][4];
#pragma unroll
    for (int m = 0; m < 4; ++m)
#pragma unroll
        for (int n = 0; n < 4; ++n) acc[m][n] = (f32x4){0.f, 0.f, 0.f, 0.f};

    // staging: op j covers phys chunks p = w*128 + j*64 + lane (lane-linear)
    const u16* agp[2]; const u16* bgp[2]; int dstoff[2];
#pragma unroll
    for (int j = 0; j < 2; ++j) {
        const int p   = w * 128 + j * 64 + lane;
        const int row = p >> 2;
        const int lc  = (p & 3) ^ (row & 3);
        agp[j] = A  + (size_t)(row0 + row) * K + lc * 8;
        bgp[j] = BT + (size_t)(col0 + row) * K + lc * 8;
        dstoff[j] = p * 8;
    }

    const int NKT = K >> 5;
    for (int kt = 0; kt < NKT; ++kt) {
        const int ko = kt * 32;
#pragma unroll
        for (int j = 0; j < 2; ++j) {
            glds16(agp[j] + ko, S + dstoff[j]);
            glds16(bgp[j] + ko, S + 4096 + dstoff[j]);
        }
        __syncthreads();
        bf16x8 av[4], bv[4];
#pragma unroll
        for (int m = 0; m < 4; ++m) {
            const int r  = wr + m * 16 + fr;
            const int ch = kq ^ (r & 3);
            av[m] = *(const bf16x8*)(S + r * 32 + ch * 8);
        }
#pragma unroll
        for (int n = 0; n < 4; ++n) {
            const int r  = wc + n * 16 + fr;
            const int ch = kq ^ (r & 3);
            bv[n] = *(const bf16x8*)(S + 4096 + r * 32 + ch * 8);
        }
#pragma unroll
        for (int m = 0; m < 4; ++m)
#pragma unroll
            for (int n = 0; n < 4; ++n)
                acc[m][n] = __builtin_amdgcn_mfma_f32_16x16x32_bf16(
                    av[m], bv[n], acc[m][n], 0, 0, 0);
        __syncthreads();
    }

    // ---- epilogues ----
    if constexpr (MODE == 7) {
        if (col0 >= 1024) {
            // V^T swizzled tile: Ct[dc][t] rows of 256B, byte ^= ((dc&7)<<4)
#pragma unroll
            for (int m = 0; m < 4; ++m)
#pragma unroll
                for (int j = 0; j < 4; ++j) {
                    const int tl = wr + m * 16 + (lane >> 4) * 4 + j;
#pragma unroll
                    for (int n = 0; n < 4; ++n) {
                        const int dc = wc + n * 16 + fr;
                        float v = acc[m][n][j] + bias[col0 + dc];
                        *(u16*)((char*)S + dc * 256 + ((tl * 2) ^ ((dc & 7) << 4))) = f2b(v);
                    }
                }
            __syncthreads();
            u16* dst = (u16*)aux + ((size_t)((row0 >> 7) * 4 + ((col0 - 1024) >> 7)) << 14);
#pragma unroll
            for (int i = 0; i < 8; ++i)
                *(uint4*)(dst + (size_t)(i * 256 + tid) * 8) =
                    *(const uint4*)((char*)S + (size_t)(i * 256 + tid) * 16);
        } else {
#pragma unroll
            for (int m = 0; m < 4; ++m)
#pragma unroll
                for (int j = 0; j < 4; ++j) {
                    const int r = row0 + wr + m * 16 + (lane >> 4) * 4 + j;
#pragma unroll
                    for (int n = 0; n < 4; ++n) {
                        const int c = col0 + wc + n * 16 + fr;
                        ((u16*)Cout)[(size_t)r * 1024 + c] = f2b(acc[m][n][j] + bias[c]);
                    }
                }
        }
    } else {
#pragma unroll
        for (int m = 0; m < 4; ++m) {
#pragma unroll
            for (int j = 0; j < 4; ++j) {
                const int r = row0 + wr + m * 16 + (lane >> 4) * 4 + j;
#pragma unroll
                for (int n = 0; n < 4; ++n) {
                    const int c = col0 + wc + n * 16 + fr;
                    float v = acc[m][n][j] + bias[c];
                    if constexpr (MODE == 2) {
                        float xs = b2f(((const u16*)addsrc)[(size_t)r * M + c]);
                        ((u16*)Cout)[(size_t)r * ldc + c] = f2b(xs + 0.3f * v);
                    } else if constexpr (MODE == 3) {
                        ((u16*)Cout)[(size_t)r * ldc + c] = f2b(fast_gelu(v));
                    } else if constexpr (MODE == 6) {
                        float pth = __shfl_xor(v, 1);
                        if ((fr & 1) == 0) {
                            float sg = 1.f / (1.f + __expf(-v));
                            float e  = __expf(2.f * pth);
                            float th = 1.f - 2.f / (e + 1.f);
                            ((u16*)Cout)[(size_t)r * ldc + (c >> 1)] = f2b(sg * th);
                        }
                    } else {  // MODE 4
                        ((u16*)Cout)[(size_t)r * ldc + c] = f2b(v);
                    }
                }
            }
        }
    }
    (void)aux; (void)addsrc;
}

// ------- weight transpose+cast: W (K,M) f32 -> WT rows (m*rmul+roff) -------
__global__ __launch_bounds__(256)
void wtrans_kernel(const float* __restrict__ W, u16* __restrict__ WT, int K, int M,
                   int rmul, int roff)
{
    __shared__ float t[32][33];
    const int m0 = blockIdx.x * 32;
    const int k0 = blockIdx.y * 32;
    const int tx = threadIdx.x;
    const int ty = threadIdx.y;
#pragma unroll
    for (int i = 0; i < 4; ++i) {
        int k = ty * 4 + i;
        t[k][tx] = W[(size_t)(k0 + k) * M + m0 + tx];
    }
    __syncthreads();
#pragma unroll
    for (int i = 0; i < 4; ++i) {
        int m = ty * 4 + i;
        WT[(size_t)((m0 + m) * rmul + roff) * K + k0 + tx] = f2b(t[tx][m]);
    }
}

__global__ void cast_f2b_kernel(const float* __restrict__ in, u16* __restrict__ out, size_t n4)
{
    size_t i = (size_t)blockIdx.x * blockDim.x + threadIdx.x;
    if (i >= n4) return;
    float4 v = reinterpret_cast<const float4*>(in)[i];
    union { u16 u[4]; uint2 d; } p;
    p.u[0] = f2b(v.x); p.u[1] = f2b(v.y); p.u[2] = f2b(v.z); p.u[3] = f2b(v.w);
    reinterpret_cast<uint2*>(out)[i] = p.d;
}

__global__ void rope_table_kernel(float* __restrict__ tabc, float* __restrict__ tabs)
{
    int idx = blockIdx.x * blockDim.x + threadIdx.x;
    if (idx >= TT * 64) return;
    int t = idx >> 6, j = idx & 63;
    float invf = expf(-(float)j * (9.210340371976184f / 64.f));
    float ang  = (float)t * invf;
    tabc[idx] = cosf(ang);
    tabs[idx] = sinf(ang);
}

__global__ void bias_build_kernel(const float* qb, const float* kb, const float* vb,
                                  const float* gb, const float* db,
                                  float* qkvb, float* gdb)
{
    int i = blockIdx.x * blockDim.x + threadIdx.x;
    if (i >= 512) return;
    qkvb[i] = qb[i]; qkvb[512 + i] = kb[i]; qkvb[1024 + i] = vb[i];
    gdb[2 * i] = gb[i]; gdb[2 * i + 1] = db[i];
}

// ---------------- MFMA attention: one block per (b,h), RoPE inline ---------
__global__ __launch_bounds__(256)
void attn_mfma_kernel(const u16* __restrict__ QKg, const u16* __restrict__ VTg,
                      u16* __restrict__ Og,
                      const float* __restrict__ tabc, const float* __restrict__ tabs)
{
    __shared__ u16 SA[128 * 128];   // Q -> P
    __shared__ u16 SB[128 * 128];   // K -> V^T
    const int h = blockIdx.x, b = blockIdx.y;
    const int tid  = threadIdx.x;
    const int lane = tid & 63;
    const int w    = tid >> 6;
    const int fr   = lane & 15;
    const int kq   = lane >> 4;
    const size_t baseq = ((size_t)(b * TT)) * 1024 + (size_t)h * HDIM;
    const size_t baseo = ((size_t)(b * TT)) * DD + (size_t)h * HDIM;

    {
        const int tg = tid >> 4;
        const int dg = tid & 15;
        const int j0 = (dg & 7) * 8;
        const bool hi = (dg & 8) != 0;
        for (int r = 0; r < 8; ++r) {
            const int t = r * 16 + tg;
            uint4 qv = *(const uint4*)(QKg + baseq + (size_t)t * 1024 + dg * 8);
            uint4 kv = *(const uint4*)(QKg + baseq + 512 + (size_t)t * 1024 + dg * 8);
            unsigned qa[4] = {qv.x, qv.y, qv.z, qv.w};
            unsigned ka[4] = {kv.x, kv.y, kv.z, kv.w};
            unsigned qb[4], kb[4];
#pragma unroll
            for (int i = 0; i < 4; ++i) {
                qb[i] = __shfl_xor((int)qa[i], 8);
                kb[i] = __shfl_xor((int)ka[i], 8);
            }
            const float* cp = tabc + t * 64 + j0;
            const float* sp = tabs + t * 64 + j0;
            u16 oq[8], ok[8];
#pragma unroll
            for (int e = 0; e < 8; ++e) {
                float fq = b2f((u16)(qa[e >> 1] >> ((e & 1) * 16)));
                float gq = b2f((u16)(qb[e >> 1] >> ((e & 1) * 16)));
                float fk = b2f((u16)(ka[e >> 1] >> ((e & 1) * 16)));
                float gk = b2f((u16)(kb[e >> 1] >> ((e & 1) * 16)));
                float c = cp[e], s = sp[e];
                oq[e] = f2b(hi ? fq * c + gq * s : fq * c - gq * s);
                ok[e] = f2b(hi ? fk * c + gk * s : fk * c - gk * s);
            }
            const int cb = (dg * 16) ^ ((t & 7) << 4);
            *(uint4*)((char*)SA + t * 256 + cb) = *(const uint4*)oq;
            *(uint4*)((char*)SB + t * 256 + cb) = *(const uint4*)ok;
        }
    }
    __syncthreads();

    f32x4 acc[2][8];
#pragma unroll
    for (int m = 0; m < 2; ++m)
#pragma unroll
        for (int n = 0; n < 8; ++n) acc[m][n] = (f32x4){0.f, 0.f, 0.f, 0.f};

    for (int k0 = 0; k0 < 128; k0 += 32) {
        const int cb = (k0 + kq * 8) * 2;
        bf16x8 af[2];
#pragma unroll
        for (int m = 0; m < 2; ++m) {
            const int row = w * 32 + m * 16 + fr;
            af[m] = *(const bf16x8*)((char*)SA + row * 256 + (cb ^ ((row & 7) << 4)));
        }
#pragma unroll
        for (int n = 0; n < 8; ++n) {
            const int row = n * 16 + fr;
            bf16x8 bf = *(const bf16x8*)((char*)SB + row * 256 + (cb ^ ((row & 7) << 4)));
            acc[0][n] = __builtin_amdgcn_mfma_f32_16x16x32_bf16(af[0], bf, acc[0][n], 0, 0, 0);
            acc[1][n] = __builtin_amdgcn_mfma_f32_16x16x32_bf16(af[1], bf, acc[1][n], 0, 0, 0);
        }
    }
    __syncthreads();

    {
        const u16* vsrc = VTg + ((size_t)(b * HH + h) << 14);
#pragma unroll
        for (int i = 0; i < 8; ++i)
            glds16(vsrc + (size_t)(i * 256 + tid) * 8,
                   SB + (size_t)(i * 256 + tid) * 8);
    }

    const float SC = 0.08838834764831845f;
#pragma unroll
    for (int m = 0; m < 2; ++m) {
#pragma unroll
        for (int j = 0; j < 4; ++j) {
            const int t = w * 32 + m * 16 + kq * 4 + j;
            float mx = -3.0e38f;
#pragma unroll
            for (int n = 0; n < 8; ++n) {
                const int s = n * 16 + fr;
                float v = acc[m][n][j];
                v = (s <= t) ? v * SC : -3.0e38f;
                acc[m][n][j] = v;
                mx = fmaxf(mx, v);
            }
            mx = fmaxf(mx, __shfl_xor(mx, 1));
            mx = fmaxf(mx, __shfl_xor(mx, 2));
            mx = fmaxf(mx, __shfl_xor(mx, 4));
            mx = fmaxf(mx, __shfl_xor(mx, 8));
            float sum = 0.f;
#pragma unroll
            for (int n = 0; n < 8; ++n) {
                float e = __expf(acc[m][n][j] - mx);
                acc[m][n][j] = e; sum += e;
            }
            sum += __shfl_xor(sum, 1); sum += __shfl_xor(sum, 2);
            sum += __shfl_xor(sum, 4); sum += __shfl_xor(sum, 8);
            const float inv = 1.f / sum;
#pragma unroll
            for (int n = 0; n < 8; ++n) {
                const int s = n * 16 + fr;
                *(u16*)((char*)SA + t * 256 + ((s * 2) ^ ((t & 7) << 4))) =
                    f2b(acc[m][n][j] * inv);
            }
        }
    }
    __syncthreads();

    f32x4 oa[2][8];
#pragma unroll
    for (int m = 0; m < 2; ++m)
#pragma unroll
        for (int n = 0; n < 8; ++n) oa[m][n] = (f32x4){0.f, 0.f, 0.f, 0.f};

    for (int k0 = 0; k0 < 128; k0 += 32) {
        const int cb = (k0 + kq * 8) * 2;
        bf16x8 pa[2];
#pragma unroll
        for (int m = 0; m < 2; ++m) {
            const int row = w * 32 + m * 16 + fr;
            pa[m] = *(const bf16x8*)((char*)SA + row * 256 + (cb ^ ((row & 7) << 4)));
        }
#pragma unroll
        for (int n = 0; n < 8; ++n) {
            const int row = n * 16 + fr;
            bf16x8 vb = *(const bf16x8*)((char*)SB + row * 256 + (cb ^ ((row & 7) << 4)));
            oa[0][n] = __builtin_amdgcn_mfma_f32_16x16x32_bf16(pa[0], vb, oa[0][n], 0, 0, 0);
            oa[1][n] = __builtin_amdgcn_mfma_f32_16x16x32_bf16(pa[1], vb, oa[1][n], 0, 0, 0);
        }
    }

#pragma unroll
    for (int m = 0; m < 2; ++m)
#pragma unroll
        for (int j = 0; j < 4; ++j) {
            const int t = w * 32 + m * 16 + kq * 4 + j;
            u16* orow = Og + baseo + (size_t)t * DD;
#pragma unroll
            for (int n = 0; n < 8; ++n)
                orow[n * 16 + fr] = f2b(oa[m][n][j]);
        }
}

// ---------------- block reduce over 512 threads (sum, sumsq) ---------------
__device__ __forceinline__ float2 blk_red512(float v, float (*red)[2], int tid)
{
    float s = v, ss = v * v;
#pragma unroll
    for (int off = 1; off < 64; off <<= 1) {
        s  += __shfl_xor(s, off);
        ss += __shfl_xor(ss, off);
    }
    if ((tid & 63) == 0) { red[tid >> 6][0] = s; red[tid >> 6][1] = ss; }
    __syncthreads();
    float S = 0.f, SS = 0.f;
#pragma unroll
    for (int w = 0; w < 8; ++w) { S += red[w][0]; SS += red[w][1]; }
    return make_float2(S, SS);
}

// ------- ln1_chain: per-batch serial LN1 + local conv + EMA ----------------
// reads xb bf16 + Oob bf16; writes Cb[row*1536 + {d, 512+d, 1024+d}] only.
__global__ __launch_bounds__(512)
void ln1_chain_kernel(const u16* __restrict__ xb, const u16* __restrict__ oo,
                      const float* __restrict__ g, const float* __restrict__ bb,
                      const float* __restrict__ lw, const float* __restrict__ lb,
                      u16* __restrict__ Cb)
{
    __shared__ float red[2][8][2];
    const int b = blockIdx.x, d = threadIdx.x;
    const float g_ = g[d], b_ = bb[d];
    const float w0 = lw[d * 4 + 0], w1 = lw[d * 4 + 1],
                w2 = lw[d * 4 + 2], w3 = lw[d * 4 + 3];
    const float lb_ = lb[d];
    const size_t rb = (size_t)b * TT;
    float h1 = 0.f, h2 = 0.f, h3 = 0.f, ema = 0.f;
    float v = b2f(xb[(rb + 0) * DD + d]) + b2f(oo[(rb + 0) * DD + d]);
    for (int t = 0; t < TT; ++t) {
        const int tn = (t < TT - 1) ? t + 1 : t;
        float vn = b2f(xb[(rb + tn) * DD + d]) + b2f(oo[(rb + tn) * DD + d]);
        float2 r = blk_red512(v, red[t & 1], d);
        float mu  = r.x * (1.f / DD);
        float var = r.y * (1.f / DD) - mu * mu;
        float x1v = (v - mu) * rsqrtf(var + 1e-5f) * g_ + b_;
        const size_t row = rb + t;
        u16* crow = Cb + row * 1536;
        crow[d] = f2b(x1v);
        crow[512 + d]  = f2b(lb_ + w3 * x1v + w2 * h1 + w1 * h2 + w0 * h3);
        ema = 0.9f * ema + 0.1f * x1v;
        crow[1024 + d] = f2b(ema);
        h3 = h2; h2 = h1; h1 = x1v;
        v = vn;
    }
}

// ------- state_chain: per-batch serial LN(dn)+cumsum+LN3 (+LN4 at t=127) ---
__global__ __launch_bounds__(512)
void state_chain_kernel(const u16* __restrict__ deltasB, const float* __restrict__ seqst,
                        const float* __restrict__ dng, const float* __restrict__ dnb,
                        const float* __restrict__ g3, const float* __restrict__ b3,
                        const float* __restrict__ g4, const float* __restrict__ b4,
                        u16* __restrict__ statesb, float* __restrict__ fstate)
{
    __shared__ float red[2][8][2];
    const int b = blockIdx.x, d = threadIdx.x;
    const float gd_ = dng[d], bd_ = dnb[d], g3_ = g3[d], b3_ = b3[d];
    const float seq = seqst[(size_t)b * DD + d];
    const size_t rb = (size_t)b * TT;
    float cum = 0.f;
    float v = b2f(deltasB[(rb + 0) * DD + d]);
    for (int t = 0; t < TT; ++t) {
        const int tn = (t < TT - 1) ? t + 1 : t;
        float vn = b2f(deltasB[(rb + tn) * DD + d]);
        float2 r0 = blk_red512(v, red[0], d);
        float mu  = r0.x * (1.f / DD);
        float var = r0.y * (1.f / DD) - mu * mu;
        float nd  = (v - mu) * rsqrtf(var + 1e-5f) * gd_ + bd_;
        cum += nd;
        float sv = seq + cum * 0.25f;
        float2 r1 = blk_red512(sv, red[1], d);
        mu  = r1.x * (1.f / DD);
        var = r1.y * (1.f / DD) - mu * mu;
        float o = (sv - mu) * rsqrtf(var + 1e-5f) * g3_ + b3_;
        statesb[(rb + t) * DD + d] = f2b(o);
        if (t == TT - 1) {
            float2 r2 = blk_red512(o, red[0], d);
            float mu4  = r2.x * (1.f / DD);
            float var4 = r2.y * (1.f / DD) - mu4 * mu4;
            fstate[(size_t)b * DD + d] = (o - mu4) * rsqrtf(var4 + 1e-5f) * g4[d] + b4[d];
        }
        v = vn;
    }
}

// ------- final LN2: x1 from Cb (stride 1536, bf16) + Fob bf16 -> f32 out ---
__global__ __launch_bounds__(256)
void ln2_kernel(const u16* __restrict__ x1cb, const u16* __restrict__ fo,
                const float* __restrict__ g, const float* __restrict__ bb,
                float* __restrict__ out)
{
    const int row = blockIdx.x;
    const int tid = threadIdx.x;
    const u16* ap = x1cb + (size_t)row * 1536;
    const u16* bp = fo   + (size_t)row * DD;
    float v0 = b2f(ap[tid])       + b2f(bp[tid]);
    float v1 = b2f(ap[tid + 256]) + b2f(bp[tid + 256]);
    float s  = v0 + v1;
    float ss = v0 * v0 + v1 * v1;
#pragma unroll
    for (int off = 1; off < 64; off <<= 1) {
        s  += __shfl_xor(s, off);
        ss += __shfl_xor(ss, off);
    }
    __shared__ float sm1[4], sm2[4];
    const int wid = tid >> 6;
    if ((tid & 63) == 0) { sm1[wid] = s; sm2[wid] = ss; }
    __syncthreads();
    s  = sm1[0] + sm1[1] + sm1[2] + sm1[3];
    ss = sm2[0] + sm2[1] + sm2[2] + sm2[3];
    const float mu  = s * (1.f / DD);
    const float var = ss * (1.f / DD) - mu * mu;
    const float r   = rsqrtf(var + 1e-5f);
    float* op = out + (size_t)row * DD;
    op[tid]       = (v0 - mu) * r * g[tid]       + bb[tid];
    op[tid + 256] = (v1 - mu) * r * g[tid + 256] + bb[tid + 256];
}

// ---------------------------------------------------------------------------
extern "C" void kernel_launch(void* const* d_in, const int* in_sizes, int n_in,
                              void* d_out, int out_size, void* d_ws, size_t ws_size,
                              hipStream_t stream)
{
    const float* x       = (const float*)d_in[0];
    const float* seqst   = (const float*)d_in[1];
    const float* q_w     = (const float*)d_in[2];
    const float* q_b     = (const float*)d_in[3];
    const float* k_w     = (const float*)d_in[4];
    const float* k_b     = (const float*)d_in[5];
    const float* v_w     = (const float*)d_in[6];
    const float* v_b     = (const float*)d_in[7];
    const float* o_w     = (const float*)d_in[8];
    const float* o_b     = (const float*)d_in[9];
    const float* local_w = (const float*)d_in[10];
    const float* local_b = (const float*)d_in[11];
    const float* delta_w = (const float*)d_in[12];
    const float* delta_b = (const float*)d_in[13];
    const float* gate_w  = (const float*)d_in[14];
    const float* gate_b  = (const float*)d_in[15];
    const float* dn_g    = (const float*)d_in[16];
    const float* dn_b    = (const float*)d_in[17];
    const float* ln1_g   = (const float*)d_in[18];
    const float* ln1_b   = (const float*)d_in[19];
    const float* ln2_g   = (const float*)d_in[20];
    const float* ln2_b   = (const float*)d_in[21];
    const float* ln3_g   = (const float*)d_in[22];
    const float* ln3_b   = (const float*)d_in[23];
    const float* ln4_g   = (const float*)d_in[24];
    const float* ln4_b   = (const float*)d_in[25];
    const float* seq_w   = (const float*)d_in[26];
    const float* seq_b   = (const float*)d_in[27];
    const float* ffn_w1  = (const float*)d_in[28];
    const float* ffn_b1  = (const float*)d_in[29];
    const float* ffn_w2  = (const float*)d_in[30];
    const float* ffn_b2  = (const float*)d_in[31];
    (void)in_sizes; (void)n_in; (void)out_size; (void)ws_size;

    float* out = (float*)d_out;
    char*  ws  = (char*)d_ws;
    const size_t MB = (size_t)1 << 20;

    // ---- region map (byte offsets in d_ws) ----
    u16*   xb      = (u16*)(ws + 0);          // [0,64M): live until ln1_chain
    u16*   QKb     = (u16*)(ws + 64 * MB);    // [64,192M): dead after attn
    u16*   VTb     = (u16*)(ws + 192 * MB);   // [192,256M): dead after attn
    u16*   attnb   = (u16*)(ws + 256 * MB);   // [256,320M): dead after o-proj
    u16*   Oob     = (u16*)(ws + 320 * MB);   // [320,384M): dead after ln1_chain
    u16*   Cb      = (u16*)(ws + 64 * MB);    // [64,256M): (N,1536); live to ln2
    u16*   deltasB = (u16*)(ws + 256 * MB);   // over attnb; dead after state_chain
    u16*   statesb = (u16*)(ws + 320 * MB);   // over Oob; dead after seq gemm
    u16*   ffn_inb = (u16*)(ws + 0);          // over xb
    u16*   hb      = (u16*)(ws + 256 * MB);   // over deltasB: 64M chunk, reused x4
    u16*   Fob     = (u16*)(ws + 320 * MB);   // over statesb
    u16*   WSq  = (u16*)(ws + 448 * MB);      // 1536x512  = 1.5M
    u16*   WSo  = (u16*)(ws + 450 * MB);      // 512x512   = 0.5M
    u16*   WSgd = (u16*)(ws + 451 * MB);      // 1024x1536 = 3M
    u16*   WSs  = (u16*)(ws + 455 * MB);      // 512x512
    u16*   WSf1 = (u16*)(ws + 456 * MB);      // 2048x512  = 2M
    u16*   WSf2 = (u16*)(ws + 458 * MB);      // 512x2048  = 2M
    float* qkvb = (float*)(ws + 460 * MB);    // 1536 f32
    float* gdb  = (float*)(ws + 461 * MB);    // 1024 f32

    float* tabc   = out + SLOT;               // tables dead after attn
    float* tabs   = tabc + TT * 64;
    float* fstate = out + SLOT;               // written by state_chain

    const size_t NE = (size_t)NROWS * DD;

    // 0. tables, casts, weight prep (all independent)
    rope_table_kernel<<<(TT * 64 + 255) / 256, 256, 0, stream>>>(tabc, tabs);
    cast_f2b_kernel<<<(unsigned)((NE / 4 + 255) / 256), 256, 0, stream>>>(x, xb, NE / 4);
    bias_build_kernel<<<2, 256, 0, stream>>>(q_b, k_b, v_b, gate_b, delta_b, qkvb, gdb);
    auto wt = [&](const float* W, u16* WT, int K, int M, int rmul, int roff) {
        wtrans_kernel<<<dim3(M / 32, K / 32), dim3(32, 8), 0, stream>>>(W, WT, K, M, rmul, roff);
    };
    wt(q_w, WSq, DD, DD, 1, 0);
    wt(k_w, WSq + (size_t)512 * DD, DD, DD, 1, 0);
    wt(v_w, WSq + (size_t)1024 * DD, DD, DD, 1, 0);
    wt(o_w, WSo, DD, DD, 1, 0);
    wt(gate_w,  WSgd, 3 * DD, DD, 2, 0);
    wt(delta_w, WSgd, 3 * DD, DD, 2, 1);
    wt(seq_w, WSs, DD, DD, 1, 0);
    wt(ffn_w1, WSf1, DD, FFD, 1, 0);
    wt(ffn_w2, WSf2, FFD, DD, 1, 0);

    // 1. fused QKV GEMM (M=1536): q|k -> QKb, v -> VTb transposed tiles
    gemm128<7><<<dim3(12, 512), 256, 0, stream>>>(
        xb, WSq, qkvb, QKb, 1024, nullptr, VTb, DD, 1536);

    // 2. fused MFMA attention (RoPE inline) -> attnb
    attn_mfma_kernel<<<dim3(HH, BB), 256, 0, stream>>>(QKb, VTb, attnb, tabc, tabs);

    // 3. o-proj -> Oob bf16
    gemm128<4><<<dim3(4, 512), 256, 0, stream>>>(
        attnb, WSo, o_b, Oob, DD, nullptr, nullptr, DD, DD);

    // 4. ln1_chain: x1/conv/ema -> Cb (x1 lives only in Cb[:,0:512])
    ln1_chain_kernel<<<BB, 512, 0, stream>>>(xb, Oob, ln1_g, ln1_b, local_w, local_b, Cb);

    // 5. fused gate/delta GEMM (M=1024 interleaved) + act -> deltasB bf16
    gemm128<6><<<dim3(8, 512), 256, 0, stream>>>(
        Cb, WSgd, gdb, deltasB, DD, nullptr, nullptr, 3 * DD, 1024);

    // 6. state_chain -> statesb bf16; LN4 -> fstate
    state_chain_kernel<<<BB, 512, 0, stream>>>(
        deltasB, seqst, dn_g, dn_b, ln3_g, ln3_b, ln4_g, ln4_b, statesb, fstate);

    // 7. ffn_in = x1(Cb) + 0.3*(states@seq_w + seq_b) -> ffn_inb bf16
    gemm128<2><<<dim3(4, 512), 256, 0, stream>>>(
        statesb, WSs, seq_b, ffn_inb, DD, Cb, nullptr, DD, 1536);

    // 8. FFN in 4 row-chunks (hb chunk 64MB stays L3-hot, region reused)
    {
        const int CH = 16384;
        for (int c = 0; c < 4; ++c) {
            const u16* Ain = ffn_inb + (size_t)c * CH * DD;
            u16* Cchunk    = Fob     + (size_t)c * CH * DD;
            gemm128<3><<<dim3(16, CH / 128), 256, 0, stream>>>(
                Ain, WSf1, ffn_b1, hb, FFD, nullptr, nullptr, DD, FFD);
            gemm128<4><<<dim3(4, CH / 128), 256, 0, stream>>>(
                hb, WSf2, ffn_b2, Cchunk, DD, nullptr, nullptr, FFD, DD);
        }
    }

    // 9. out = LN2(x1(Cb) + ffn_out) -> d_out
    ln2_kernel<<<NROWS, 256, 0, stream>>>(Cb, Fob, ln2_g, ln2_b, out);
}

// Round 11
// 1777.739 us; speedup vs baseline: 1.0281x; 1.0281x over previous
//
#include <hip/hip_runtime.h>
#include <cstddef>
#include <cstdint>

#define BB   512
#define TT   128
#define DD   512
#define HH   4
#define HDIM 128
#define FFD  2048
#define NROWS (BB * TT)                 // 65536 rows
#define SLOT ((size_t)NROWS * DD)       // 33554432 floats = 128 MiB

typedef unsigned short u16;
typedef __bf16 bf16x8 __attribute__((ext_vector_type(8)));
typedef float  f32x4  __attribute__((ext_vector_type(4)));

__device__ __forceinline__ u16 f2b(float x) {
    union { float f; unsigned u; } v; v.f = x;
    unsigned r = v.u + 0x7FFFu + ((v.u >> 16) & 1u);
    return (u16)(r >> 16);
}
__device__ __forceinline__ float b2f(u16 u) {
    union { unsigned u; float f; } v; v.u = (unsigned)u << 16; return v.f;
}
__device__ __forceinline__ float fast_gelu(float v) {
    float t = v * (0.7978845608028654f + 0.0356774081f * v * v);
    float e = __expf(2.f * t);
    float th = 1.f - 2.f / (e + 1.f);          // tanh(t)
    return 0.5f * v * (1.f + th);
}
__device__ __forceinline__ void glds16(const void* g, void* l) {
    __builtin_amdgcn_global_load_lds(
        (const __attribute__((address_space(1))) void*)g,
        (__attribute__((address_space(3))) void*)l, 16, 0, 0);
}

#define BAR() asm volatile("s_barrier" ::: "memory")
#define MM(ACC, AV, BV) \
    ACC = __builtin_amdgcn_mfma_f32_16x16x32_bf16(AV, BV, ACC, 0, 0, 0)

// ============ 256x256 quadrant-phase bf16 GEMM (R6-best, 1655-run) ==========
// MODE 2: bf16 out = addsrc_bf16[r*M+c] + 0.3*C. MODE 3: bf16 gelu(C).
// MODE 4: bf16 C. MODE 6: gate/delta interleave -> sigmoid*tanh @ c>>1.
template<int MODE>
__global__ __launch_bounds__(512, 2)
void gemm256(const u16* __restrict__ A, const u16* __restrict__ BT,
             const float* __restrict__ bias, void* __restrict__ Cout, int ldc,
             const u16* __restrict__ addsrc, int K, int M)
{
    __shared__ u16 S[65536];   // 128 KiB
    const int tid = threadIdx.x;
    const int gx  = gridDim.x;               // M/256
    const int nwg = gx * gridDim.y;
    int orig = blockIdx.y * gx + blockIdx.x;
    orig = (orig & 7) * (nwg >> 3) + (orig >> 3);   // XCD swizzle (nwg%8==0)
    const int row0 = (orig / gx) * 256;
    const int col0 = (orig % gx) * 256;

    const int lane = tid & 63;
    const int wid  = tid >> 6;
    const int wm   = wid >> 2;       // row half (0/1)
    const int wn   = wid & 3;        // col quarter (0..3)
    const int fr   = lane & 15;
    const int kq   = lane >> 4;      // 0..3

    // staging: phys chunk c -> logical l = c ^ (((c>>5)&1)<<1)  (16B chunks)
    const int c0 = wid * 128 + lane;
    const int c1 = c0 + 64;
    const int l0 = c0 ^ (((c0 >> 5) & 1) << 1);
    const int l1 = c1 ^ (((c1 >> 5) & 1) << 1);
    const int sr0 = l0 >> 2, sk0 = (l0 & 3) * 8;
    const int sr1 = l1 >> 2, sk1 = (l1 & 3) * 8;
    const u16* ApG = A  + (size_t)row0 * K;
    const u16* BpG = BT + (size_t)col0 * K;

    auto stA = [&](int kt, int kh) {
        char* slot = (char*)S + ((((kt & 1) << 1) + kh) << 14);
        const u16* g = ApG + kt * 64 + kh * 32;
        glds16(g + (size_t)sr0 * K + sk0, slot + c0 * 16);
        glds16(g + (size_t)sr1 * K + sk1, slot + c1 * 16);
    };
    auto stB = [&](int kt, int kh) {
        char* slot = (char*)S + 65536 + ((((kt & 1) << 1) + kh) << 14);
        const u16* g = BpG + kt * 64 + kh * 32;
        glds16(g + (size_t)sr0 * K + sk0, slot + c0 * 16);
        glds16(g + (size_t)sr1 * K + sk1, slot + c1 * 16);
    };
    auto rdA = [&](int p, int kh, int m) -> bf16x8 {
        const int row = wm * 128 + m * 16 + fr;
        const int L = (row * 64 + kq * 16) ^ (((row >> 3) & 1) << 5);
        return *(const bf16x8*)((char*)S + (((p << 1) + kh) << 14) + L);
    };
    auto rdB = [&](int p, int kh, int n) -> bf16x8 {
        const int col = wn * 64 + n * 16 + fr;
        const int L = (col * 64 + kq * 16) ^ (((col >> 3) & 1) << 5);
        return *(const bf16x8*)((char*)S + 65536 + (((p << 1) + kh) << 14) + L);
    };

    f32x4 acc[8][4];
#pragma unroll
    for (int m = 0; m < 8; ++m)
#pragma unroll
        for (int n = 0; n < 4; ++n) acc[m][n] = (f32x4){0.f, 0.f, 0.f, 0.f};

    const int NKT = K >> 6;

    // prologue: tile0 (4 slabs) + B(1,0), B(1,1), A(1,0)
    stA(0, 0); stA(0, 1); stB(0, 0); stB(0, 1);
    stB(1, 0); stB(1, 1); stA(1, 0);
    asm volatile("s_waitcnt vmcnt(6)" ::: "memory");
    BAR();

    for (int kt = 0; kt < NKT; ++kt) {
        const int p = kt & 1;
        const bool s1 = (kt + 1 < NKT);
        const bool s2 = (kt + 2 < NKT);
        bf16x8 a0, a1, a2, a3, a4, a5, a6, a7;         // A frags [kh][m-quarter]
        bf16x8 b00, b01, b02, b03, b10, b11, b12, b13; // B frags [kh][n]

        // ---- ph1: (m0-3, n0-1); stage A(kt+1,1) -> slot p^1 ----
        if (s1) stA(kt + 1, 1);
        a0 = rdA(p, 0, 0); a1 = rdA(p, 0, 1); a2 = rdA(p, 0, 2); a3 = rdA(p, 0, 3);
        a4 = rdA(p, 1, 0); a5 = rdA(p, 1, 1); a6 = rdA(p, 1, 2); a7 = rdA(p, 1, 3);
        b00 = rdB(p, 0, 0); b01 = rdB(p, 0, 1);
        b10 = rdB(p, 1, 0); b11 = rdB(p, 1, 1);
        BAR();
        __builtin_amdgcn_s_setprio(1);
        MM(acc[0][0], a0, b00); MM(acc[0][1], a0, b01);
        MM(acc[1][0], a1, b00); MM(acc[1][1], a1, b01);
        MM(acc[2][0], a2, b00); MM(acc[2][1], a2, b01);
        MM(acc[3][0], a3, b00); MM(acc[3][1], a3, b01);
        MM(acc[0][0], a4, b10); MM(acc[0][1], a4, b11);
        MM(acc[1][0], a5, b10); MM(acc[1][1], a5, b11);
        MM(acc[2][0], a6, b10); MM(acc[2][1], a6, b11);
        MM(acc[3][0], a7, b10); MM(acc[3][1], a7, b11);
        __builtin_amdgcn_s_setprio(0);
        BAR();

        // ---- ph2: (m0-3, n2-3); A held; read B n2-3 ----
        b02 = rdB(p, 0, 2); b03 = rdB(p, 0, 3);
        b12 = rdB(p, 1, 2); b13 = rdB(p, 1, 3);
        BAR();
        __builtin_amdgcn_s_setprio(1);
        MM(acc[0][2], a0, b02); MM(acc[0][3], a0, b03);
        MM(acc[1][2], a1, b02); MM(acc[1][3], a1, b03);
        MM(acc[2][2], a2, b02); MM(acc[2][3], a2, b03);
        MM(acc[3][2], a3, b02); MM(acc[3][3], a3, b03);
        MM(acc[0][2], a4, b12); MM(acc[0][3], a4, b13);
        MM(acc[1][2], a5, b12); MM(acc[1][3], a5, b13);
        MM(acc[2][2], a6, b12); MM(acc[2][3], a6, b13);
        MM(acc[3][2], a7, b12); MM(acc[3][3], a7, b13);
        __builtin_amdgcn_s_setprio(0);
        BAR();

        // ---- ph3: (m4-7, n0-1); stage B(kt+2,0) ----
        if (s2) stB(kt + 2, 0);
        a0 = rdA(p, 0, 4); a1 = rdA(p, 0, 5); a2 = rdA(p, 0, 6); a3 = rdA(p, 0, 7);
        a4 = rdA(p, 1, 4); a5 = rdA(p, 1, 5); a6 = rdA(p, 1, 6); a7 = rdA(p, 1, 7);
        BAR();
        __builtin_amdgcn_s_setprio(1);
        MM(acc[4][0], a0, b00); MM(acc[4][1], a0, b01);
        MM(acc[5][0], a1, b00); MM(acc[5][1], a1, b01);
        MM(acc[6][0], a2, b00); MM(acc[6][1], a2, b01);
        MM(acc[7][0], a3, b00); MM(acc[7][1], a3, b01);
        MM(acc[4][0], a4, b10); MM(acc[4][1], a4, b11);
        MM(acc[5][0], a5, b10); MM(acc[5][1], a5, b11);
        MM(acc[6][0], a6, b10); MM(acc[6][1], a6, b11);
        MM(acc[7][0], a7, b10); MM(acc[7][1], a7, b11);
        __builtin_amdgcn_s_setprio(0);
        BAR();

        // ---- ph4: (m4-7, n2-3); stage B(kt+2,1)+A(kt+2,0) ----
        if (s2) { stB(kt + 2, 1); stA(kt + 2, 0); }
        __builtin_amdgcn_s_setprio(1);
        MM(acc[4][2], a0, b02); MM(acc[4][3], a0, b03);
        MM(acc[5][2], a1, b02); MM(acc[5][3], a1, b03);
        MM(acc[6][2], a2, b02); MM(acc[6][3], a2, b03);
        MM(acc[7][2], a3, b02); MM(acc[7][3], a3, b03);
        MM(acc[4][2], a4, b12); MM(acc[4][3], a4, b13);
        MM(acc[5][2], a5, b12); MM(acc[5][3], a5, b13);
        MM(acc[6][2], a6, b12); MM(acc[6][3], a6, b13);
        MM(acc[7][2], a7, b12); MM(acc[7][3], a7, b13);
        __builtin_amdgcn_s_setprio(0);
        if (s2)      asm volatile("s_waitcnt vmcnt(6)" ::: "memory");
        else if (s1) asm volatile("s_waitcnt vmcnt(0)" ::: "memory");
        if (s1) BAR();
    }

    // ---- epilogue ----
#pragma unroll
    for (int m = 0; m < 8; ++m) {
#pragma unroll
        for (int jj = 0; jj < 4; ++jj) {
            const int r = row0 + wm * 128 + m * 16 + kq * 4 + jj;
#pragma unroll
            for (int n = 0; n < 4; ++n) {
                const int c = col0 + wn * 64 + n * 16 + fr;
                float v = acc[m][n][jj] + bias[c];
                if constexpr (MODE == 2) {
                    float xs = b2f(addsrc[(size_t)r * M + c]);
                    ((u16*)Cout)[(size_t)r * ldc + c] = f2b(xs + 0.3f * v);
                } else if constexpr (MODE == 3) {
                    ((u16*)Cout)[(size_t)r * ldc + c] = f2b(fast_gelu(v));
                } else if constexpr (MODE == 6) {
                    float pth = __shfl_xor(v, 1);
                    if ((fr & 1) == 0) {
                        float sg = 1.f / (1.f + __expf(-v));
                        float e  = __expf(2.f * pth);
                        float th = 1.f - 2.f / (e + 1.f);
                        ((u16*)Cout)[(size_t)r * ldc + (c >> 1)] = f2b(sg * th);
                    }
                } else {  // MODE 4
                    ((u16*)Cout)[(size_t)r * ldc + c] = f2b(v);
                }
            }
        }
    }
}

// ---------------- 128x128 bf16 GEMM (QKV only, MODE 7, R6 dbuf) ------------
template<int MODE>
__global__ __launch_bounds__(256)
void gemm_bf16(const u16* __restrict__ A, const u16* __restrict__ BT,
               const float* __restrict__ bias, void* __restrict__ Cout, int ldc,
               const float* __restrict__ addsrc, void* __restrict__ aux,
               int K, int M)
{
    __shared__ u16 smem[16384];
    const int tid = threadIdx.x;
    const int gx  = gridDim.x;
    const int nwg = gx * gridDim.y;
    int orig = blockIdx.y * gx + blockIdx.x;
    if ((nwg & 7) == 0) orig = (orig & 7) * (nwg >> 3) + (orig >> 3);
    const int row0 = (orig / gx) * 128;
    const int col0 = (orig % gx) * 128;

    const int lane = tid & 63;
    const int w    = tid >> 6;
    const int wr   = (w >> 1) * 64;
    const int wc   = (w & 1) * 64;
    const int fr   = lane & 15;
    const int kg   = (lane >> 4) * 8;

    f32x4 acc[4][4];
#pragma unroll
    for (int m = 0; m < 4; ++m)
#pragma unroll
        for (int n = 0; n < 4; ++n) acc[m][n] = (f32x4){0.f, 0.f, 0.f, 0.f};

    const int srow = tid >> 2;
    const int skb  = (tid & 3) * 8;
    const u16* Ag = A  + (size_t)(row0 + srow) * K + skb;
    const u16* Bg = BT + (size_t)(col0 + srow) * K + skb;
    const int soff = srow * 32 + skb;

    auto stage = [&](int kt, int buf) {
        const int ko = kt * 32;
        u16* as = smem + buf * 8192 + soff;
        u16* bs = smem + buf * 8192 + 4096 + soff;
        glds16(Ag + ko,                  as);
        glds16(Ag + (size_t)64 * K + ko, as + 2048);
        glds16(Bg + ko,                  bs);
        glds16(Bg + (size_t)64 * K + ko, bs + 2048);
    };

    const int nk = K >> 5;
    stage(0, 0);
    for (int k = 0; k < nk; ++k) {
        if (k + 1 < nk) {
            stage(k + 1, (k + 1) & 1);
            asm volatile("s_waitcnt vmcnt(4)" ::: "memory");
        } else {
            asm volatile("s_waitcnt vmcnt(0)" ::: "memory");
        }
        __syncthreads();
        const u16* As = smem + (k & 1) * 8192;
        const u16* Bs = As + 4096;
        bf16x8 af[4], bfr[4];
#pragma unroll
        for (int m = 0; m < 4; ++m)
            af[m] = *reinterpret_cast<const bf16x8*>(&As[(wr + m * 16 + fr) * 32 + kg]);
#pragma unroll
        for (int n = 0; n < 4; ++n)
            bfr[n] = *reinterpret_cast<const bf16x8*>(&Bs[(wc + n * 16 + fr) * 32 + kg]);
#pragma unroll
        for (int m = 0; m < 4; ++m)
#pragma unroll
            for (int n = 0; n < 4; ++n)
                acc[m][n] = __builtin_amdgcn_mfma_f32_16x16x32_bf16(af[m], bfr[n], acc[m][n], 0, 0, 0);
        __syncthreads();
    }

    if constexpr (MODE == 7) {
        if (col0 >= 1024) {
            // V^T swizzled tile: Ct[dc][t] rows of 256B, byte ^= ((dc&7)<<4)
#pragma unroll
            for (int m = 0; m < 4; ++m)
#pragma unroll
                for (int j = 0; j < 4; ++j) {
                    const int tl = wr + m * 16 + (lane >> 4) * 4 + j;
#pragma unroll
                    for (int n = 0; n < 4; ++n) {
                        const int dc = wc + n * 16 + fr;
                        float v = acc[m][n][j] + bias[col0 + dc];
                        *(u16*)((char*)smem + dc * 256 + ((tl * 2) ^ ((dc & 7) << 4))) = f2b(v);
                    }
                }
            __syncthreads();
            u16* dst = (u16*)aux + ((size_t)((row0 >> 7) * 4 + ((col0 - 1024) >> 7)) << 14);
#pragma unroll
            for (int i = 0; i < 8; ++i)
                *(uint4*)(dst + (size_t)(i * 256 + tid) * 8) =
                    *(const uint4*)((char*)smem + (size_t)(i * 256 + tid) * 16);
        } else {
#pragma unroll
            for (int m = 0; m < 4; ++m)
#pragma unroll
                for (int j = 0; j < 4; ++j) {
                    const int r = row0 + wr + m * 16 + (lane >> 4) * 4 + j;
#pragma unroll
                    for (int n = 0; n < 4; ++n) {
                        const int c = col0 + wc + n * 16 + fr;
                        ((u16*)Cout)[(size_t)r * 1024 + c] = f2b(acc[m][n][j] + bias[c]);
                    }
                }
        }
    }
    (void)ldc; (void)addsrc;
}

// ------- weight transpose+cast: W (K,M) f32 -> WT rows (m*rmul+roff) -------
__global__ __launch_bounds__(256)
void wtrans_kernel(const float* __restrict__ W, u16* __restrict__ WT, int K, int M,
                   int rmul, int roff)
{
    __shared__ float t[32][33];
    const int m0 = blockIdx.x * 32;
    const int k0 = blockIdx.y * 32;
    const int tx = threadIdx.x;
    const int ty = threadIdx.y;
#pragma unroll
    for (int i = 0; i < 4; ++i) {
        int k = ty * 4 + i;
        t[k][tx] = W[(size_t)(k0 + k) * M + m0 + tx];
    }
    __syncthreads();
#pragma unroll
    for (int i = 0; i < 4; ++i) {
        int m = ty * 4 + i;
        WT[(size_t)((m0 + m) * rmul + roff) * K + k0 + tx] = f2b(t[tx][m]);
    }
}

__global__ void cast_f2b_kernel(const float* __restrict__ in, u16* __restrict__ out, size_t n4)
{
    size_t i = (size_t)blockIdx.x * blockDim.x + threadIdx.x;
    if (i >= n4) return;
    float4 v = reinterpret_cast<const float4*>(in)[i];
    union { u16 u[4]; uint2 d; } p;
    p.u[0] = f2b(v.x); p.u[1] = f2b(v.y); p.u[2] = f2b(v.z); p.u[3] = f2b(v.w);
    reinterpret_cast<uint2*>(out)[i] = p.d;
}

__global__ void rope_table_kernel(float* __restrict__ tabc, float* __restrict__ tabs)
{
    int idx = blockIdx.x * blockDim.x + threadIdx.x;
    if (idx >= TT * 64) return;
    int t = idx >> 6, j = idx & 63;
    float invf = expf(-(float)j * (9.210340371976184f / 64.f));
    float ang  = (float)t * invf;
    tabc[idx] = cosf(ang);
    tabs[idx] = sinf(ang);
}

__global__ void bias_build_kernel(const float* qb, const float* kb, const float* vb,
                                  const float* gb, const float* db,
                                  float* qkvb, float* gdb)
{
    int i = blockIdx.x * blockDim.x + threadIdx.x;
    if (i >= 512) return;
    qkvb[i] = qb[i]; qkvb[512 + i] = kb[i]; qkvb[1024 + i] = vb[i];
    gdb[2 * i] = gb[i]; gdb[2 * i + 1] = db[i];
}

// ---------------- MFMA attention: one block per (b,h), RoPE inline ---------
__global__ __launch_bounds__(256)
void attn_mfma_kernel(const u16* __restrict__ QKg, const u16* __restrict__ VTg,
                      u16* __restrict__ Og,
                      const float* __restrict__ tabc, const float* __restrict__ tabs)
{
    __shared__ u16 SA[128 * 128];   // Q -> P
    __shared__ u16 SB[128 * 128];   // K -> V^T
    const int h = blockIdx.x, b = blockIdx.y;
    const int tid  = threadIdx.x;
    const int lane = tid & 63;
    const int w    = tid >> 6;
    const int fr   = lane & 15;
    const int kq   = lane >> 4;
    const size_t baseq = ((size_t)(b * TT)) * 1024 + (size_t)h * HDIM;
    const size_t baseo = ((size_t)(b * TT)) * DD + (size_t)h * HDIM;

    {
        const int tg = tid >> 4;
        const int dg = tid & 15;
        const int j0 = (dg & 7) * 8;
        const bool hi = (dg & 8) != 0;
        for (int r = 0; r < 8; ++r) {
            const int t = r * 16 + tg;
            uint4 qv = *(const uint4*)(QKg + baseq + (size_t)t * 1024 + dg * 8);
            uint4 kv = *(const uint4*)(QKg + baseq + 512 + (size_t)t * 1024 + dg * 8);
            unsigned qa[4] = {qv.x, qv.y, qv.z, qv.w};
            unsigned ka[4] = {kv.x, kv.y, kv.z, kv.w};
            unsigned qb[4], kb[4];
#pragma unroll
            for (int i = 0; i < 4; ++i) {
                qb[i] = __shfl_xor((int)qa[i], 8);
                kb[i] = __shfl_xor((int)ka[i], 8);
            }
            const float* cp = tabc + t * 64 + j0;
            const float* sp = tabs + t * 64 + j0;
            u16 oq[8], ok[8];
#pragma unroll
            for (int e = 0; e < 8; ++e) {
                float fq = b2f((u16)(qa[e >> 1] >> ((e & 1) * 16)));
                float gq = b2f((u16)(qb[e >> 1] >> ((e & 1) * 16)));
                float fk = b2f((u16)(ka[e >> 1] >> ((e & 1) * 16)));
                float gk = b2f((u16)(kb[e >> 1] >> ((e & 1) * 16)));
                float c = cp[e], s = sp[e];
                oq[e] = f2b(hi ? fq * c + gq * s : fq * c - gq * s);
                ok[e] = f2b(hi ? fk * c + gk * s : fk * c - gk * s);
            }
            const int cb = (dg * 16) ^ ((t & 7) << 4);
            *(uint4*)((char*)SA + t * 256 + cb) = *(const uint4*)oq;
            *(uint4*)((char*)SB + t * 256 + cb) = *(const uint4*)ok;
        }
    }
    __syncthreads();

    f32x4 acc[2][8];
#pragma unroll
    for (int m = 0; m < 2; ++m)
#pragma unroll
        for (int n = 0; n < 8; ++n) acc[m][n] = (f32x4){0.f, 0.f, 0.f, 0.f};

    for (int k0 = 0; k0 < 128; k0 += 32) {
        const int cb = (k0 + kq * 8) * 2;
        bf16x8 af[2];
#pragma unroll
        for (int m = 0; m < 2; ++m) {
            const int row = w * 32 + m * 16 + fr;
            af[m] = *(const bf16x8*)((char*)SA + row * 256 + (cb ^ ((row & 7) << 4)));
        }
#pragma unroll
        for (int n = 0; n < 8; ++n) {
            const int row = n * 16 + fr;
            bf16x8 bf = *(const bf16x8*)((char*)SB + row * 256 + (cb ^ ((row & 7) << 4)));
            acc[0][n] = __builtin_amdgcn_mfma_f32_16x16x32_bf16(af[0], bf, acc[0][n], 0, 0, 0);
            acc[1][n] = __builtin_amdgcn_mfma_f32_16x16x32_bf16(af[1], bf, acc[1][n], 0, 0, 0);
        }
    }
    __syncthreads();

    {
        const u16* vsrc = VTg + ((size_t)(b * HH + h) << 14);
#pragma unroll
        for (int i = 0; i < 8; ++i)
            glds16(vsrc + (size_t)(i * 256 + tid) * 8,
                   SB + (size_t)(i * 256 + tid) * 8);
    }

    const float SC = 0.08838834764831845f;
#pragma unroll
    for (int m = 0; m < 2; ++m) {
#pragma unroll
        for (int j = 0; j < 4; ++j) {
            const int t = w * 32 + m * 16 + kq * 4 + j;
            float mx = -3.0e38f;
#pragma unroll
            for (int n = 0; n < 8; ++n) {
                const int s = n * 16 + fr;
                float v = acc[m][n][j];
                v = (s <= t) ? v * SC : -3.0e38f;
                acc[m][n][j] = v;
                mx = fmaxf(mx, v);
            }
            mx = fmaxf(mx, __shfl_xor(mx, 1));
            mx = fmaxf(mx, __shfl_xor(mx, 2));
            mx = fmaxf(mx, __shfl_xor(mx, 4));
            mx = fmaxf(mx, __shfl_xor(mx, 8));
            float sum = 0.f;
#pragma unroll
            for (int n = 0; n < 8; ++n) {
                float e = __expf(acc[m][n][j] - mx);
                acc[m][n][j] = e; sum += e;
            }
            sum += __shfl_xor(sum, 1); sum += __shfl_xor(sum, 2);
            sum += __shfl_xor(sum, 4); sum += __shfl_xor(sum, 8);
            const float inv = 1.f / sum;
#pragma unroll
            for (int n = 0; n < 8; ++n) {
                const int s = n * 16 + fr;
                *(u16*)((char*)SA + t * 256 + ((s * 2) ^ ((t & 7) << 4))) =
                    f2b(acc[m][n][j] * inv);
            }
        }
    }
    __syncthreads();

    f32x4 oa[2][8];
#pragma unroll
    for (int m = 0; m < 2; ++m)
#pragma unroll
        for (int n = 0; n < 8; ++n) oa[m][n] = (f32x4){0.f, 0.f, 0.f, 0.f};

    for (int k0 = 0; k0 < 128; k0 += 32) {
        const int cb = (k0 + kq * 8) * 2;
        bf16x8 pa[2];
#pragma unroll
        for (int m = 0; m < 2; ++m) {
            const int row = w * 32 + m * 16 + fr;
            pa[m] = *(const bf16x8*)((char*)SA + row * 256 + (cb ^ ((row & 7) << 4)));
        }
#pragma unroll
        for (int n = 0; n < 8; ++n) {
            const int row = n * 16 + fr;
            bf16x8 vb = *(const bf16x8*)((char*)SB + row * 256 + (cb ^ ((row & 7) << 4)));
            oa[0][n] = __builtin_amdgcn_mfma_f32_16x16x32_bf16(pa[0], vb, oa[0][n], 0, 0, 0);
            oa[1][n] = __builtin_amdgcn_mfma_f32_16x16x32_bf16(pa[1], vb, oa[1][n], 0, 0, 0);
        }
    }

#pragma unroll
    for (int m = 0; m < 2; ++m)
#pragma unroll
        for (int j = 0; j < 4; ++j) {
            const int t = w * 32 + m * 16 + kq * 4 + j;
            u16* orow = Og + baseo + (size_t)t * DD;
#pragma unroll
            for (int n = 0; n < 8; ++n)
                orow[n * 16 + fr] = f2b(oa[m][n][j]);
        }
}

// ---------------- block reduce over 512 threads (sum, sumsq) ---------------
__device__ __forceinline__ float2 blk_red512(float v, float (*red)[2], int tid)
{
    float s = v, ss = v * v;
#pragma unroll
    for (int off = 1; off < 64; off <<= 1) {
        s  += __shfl_xor(s, off);
        ss += __shfl_xor(ss, off);
    }
    if ((tid & 63) == 0) { red[tid >> 6][0] = s; red[tid >> 6][1] = ss; }
    __syncthreads();
    float S = 0.f, SS = 0.f;
#pragma unroll
    for (int w = 0; w < 8; ++w) { S += red[w][0]; SS += red[w][1]; }
    return make_float2(S, SS);
}

// ------- ln1_chain: per-batch serial LN1 + local conv + EMA (bf16 in) ------
__global__ __launch_bounds__(512)
void ln1_chain_kernel(const u16* __restrict__ xb, const u16* __restrict__ oo,
                      const float* __restrict__ g, const float* __restrict__ bb,
                      const float* __restrict__ lw, const float* __restrict__ lb,
                      u16* __restrict__ Cb)
{
    __shared__ float red[2][8][2];
    const int b = blockIdx.x, d = threadIdx.x;
    const float g_ = g[d], b_ = bb[d];
    const float w0 = lw[d * 4 + 0], w1 = lw[d * 4 + 1],
                w2 = lw[d * 4 + 2], w3 = lw[d * 4 + 3];
    const float lb_ = lb[d];
    const size_t rb = (size_t)b * TT;
    float h1 = 0.f, h2 = 0.f, h3 = 0.f, ema = 0.f;
    float v = b2f(xb[(rb + 0) * DD + d]) + b2f(oo[(rb + 0) * DD + d]);
    for (int t = 0; t < TT; ++t) {
        const int tn = (t < TT - 1) ? t + 1 : t;
        float vn = b2f(xb[(rb + tn) * DD + d]) + b2f(oo[(rb + tn) * DD + d]);
        float2 r = blk_red512(v, red[t & 1], d);
        float mu  = r.x * (1.f / DD);
        float var = r.y * (1.f / DD) - mu * mu;
        float x1v = (v - mu) * rsqrtf(var + 1e-5f) * g_ + b_;
        const size_t row = rb + t;
        u16* crow = Cb + row * 1536;
        crow[d] = f2b(x1v);
        crow[512 + d]  = f2b(lb_ + w3 * x1v + w2 * h1 + w1 * h2 + w0 * h3);
        ema = 0.9f * ema + 0.1f * x1v;
        crow[1024 + d] = f2b(ema);
        h3 = h2; h2 = h1; h1 = x1v;
        v = vn;
    }
}

// ------- state_chain: per-batch serial LN(dn)+cumsum+LN3 (+LN4 at t=127) ---
__global__ __launch_bounds__(512)
void state_chain_kernel(const u16* __restrict__ deltasB, const float* __restrict__ seqst,
                        const float* __restrict__ dng, const float* __restrict__ dnb,
                        const float* __restrict__ g3, const float* __restrict__ b3,
                        const float* __restrict__ g4, const float* __restrict__ b4,
                        u16* __restrict__ statesb, float* __restrict__ fstate)
{
    __shared__ float red[2][8][2];
    const int b = blockIdx.x, d = threadIdx.x;
    const float gd_ = dng[d], bd_ = dnb[d], g3_ = g3[d], b3_ = b3[d];
    const float seq = seqst[(size_t)b * DD + d];
    const size_t rb = (size_t)b * TT;
    float cum = 0.f;
    float v = b2f(deltasB[(rb + 0) * DD + d]);
    for (int t = 0; t < TT; ++t) {
        const int tn = (t < TT - 1) ? t + 1 : t;
        float vn = b2f(deltasB[(rb + tn) * DD + d]);
        float2 r0 = blk_red512(v, red[0], d);
        float mu  = r0.x * (1.f / DD);
        float var = r0.y * (1.f / DD) - mu * mu;
        float nd  = (v - mu) * rsqrtf(var + 1e-5f) * gd_ + bd_;
        cum += nd;
        float sv = seq + cum * 0.25f;
        float2 r1 = blk_red512(sv, red[1], d);
        mu  = r1.x * (1.f / DD);
        var = r1.y * (1.f / DD) - mu * mu;
        float o = (sv - mu) * rsqrtf(var + 1e-5f) * g3_ + b3_;
        statesb[(rb + t) * DD + d] = f2b(o);
        if (t == TT - 1) {
            float2 r2 = blk_red512(o, red[0], d);
            float mu4  = r2.x * (1.f / DD);
            float var4 = r2.y * (1.f / DD) - mu4 * mu4;
            fstate[(size_t)b * DD + d] = (o - mu4) * rsqrtf(var4 + 1e-5f) * g4[d] + b4[d];
        }
        v = vn;
    }
}

// ------- final LN2: x1 from Cb (stride 1536, bf16) + Fob bf16 -> f32 out ---
__global__ __launch_bounds__(256)
void ln2_kernel(const u16* __restrict__ x1cb, const u16* __restrict__ fo,
                const float* __restrict__ g, const float* __restrict__ bb,
                float* __restrict__ out)
{
    const int row = blockIdx.x;
    const int tid = threadIdx.x;
    const u16* ap = x1cb + (size_t)row * 1536;
    const u16* bp = fo   + (size_t)row * DD;
    float v0 = b2f(ap[tid])       + b2f(bp[tid]);
    float v1 = b2f(ap[tid + 256]) + b2f(bp[tid + 256]);
    float s  = v0 + v1;
    float ss = v0 * v0 + v1 * v1;
#pragma unroll
    for (int off = 1; off < 64; off <<= 1) {
        s  += __shfl_xor(s, off);
        ss += __shfl_xor(ss, off);
    }
    __shared__ float sm1[4], sm2[4];
    const int wid = tid >> 6;
    if ((tid & 63) == 0) { sm1[wid] = s; sm2[wid] = ss; }
    __syncthreads();
    s  = sm1[0] + sm1[1] + sm1[2] + sm1[3];
    ss = sm2[0] + sm2[1] + sm2[2] + sm2[3];
    const float mu  = s * (1.f / DD);
    const float var = ss * (1.f / DD) - mu * mu;
    const float r   = rsqrtf(var + 1e-5f);
    float* op = out + (size_t)row * DD;
    op[tid]       = (v0 - mu) * r * g[tid]       + bb[tid];
    op[tid + 256] = (v1 - mu) * r * g[tid + 256] + bb[tid + 256];
}

// ---------------------------------------------------------------------------
extern "C" void kernel_launch(void* const* d_in, const int* in_sizes, int n_in,
                              void* d_out, int out_size, void* d_ws, size_t ws_size,
                              hipStream_t stream)
{
    const float* x       = (const float*)d_in[0];
    const float* seqst   = (const float*)d_in[1];
    const float* q_w     = (const float*)d_in[2];
    const float* q_b     = (const float*)d_in[3];
    const float* k_w     = (const float*)d_in[4];
    const float* k_b     = (const float*)d_in[5];
    const float* v_w     = (const float*)d_in[6];
    const float* v_b     = (const float*)d_in[7];
    const float* o_w     = (const float*)d_in[8];
    const float* o_b     = (const float*)d_in[9];
    const float* local_w = (const float*)d_in[10];
    const float* local_b = (const float*)d_in[11];
    const float* delta_w = (const float*)d_in[12];
    const float* delta_b = (const float*)d_in[13];
    const float* gate_w  = (const float*)d_in[14];
    const float* gate_b  = (const float*)d_in[15];
    const float* dn_g    = (const float*)d_in[16];
    const float* dn_b    = (const float*)d_in[17];
    const float* ln1_g   = (const float*)d_in[18];
    const float* ln1_b   = (const float*)d_in[19];
    const float* ln2_g   = (const float*)d_in[20];
    const float* ln2_b   = (const float*)d_in[21];
    const float* ln3_g   = (const float*)d_in[22];
    const float* ln3_b   = (const float*)d_in[23];
    const float* ln4_g   = (const float*)d_in[24];
    const float* ln4_b   = (const float*)d_in[25];
    const float* seq_w   = (const float*)d_in[26];
    const float* seq_b   = (const float*)d_in[27];
    const float* ffn_w1  = (const float*)d_in[28];
    const float* ffn_b1  = (const float*)d_in[29];
    const float* ffn_w2  = (const float*)d_in[30];
    const float* ffn_b2  = (const float*)d_in[31];
    (void)in_sizes; (void)n_in; (void)out_size; (void)ws_size;

    float* out = (float*)d_out;
    char*  ws  = (char*)d_ws;
    const size_t MB = (size_t)1 << 20;

    // ---- region map (byte offsets in d_ws) ----
    u16*   xb      = (u16*)(ws + 0);          // [0,64M): live until ln1_chain
    u16*   QKb     = (u16*)(ws + 64 * MB);    // [64,192M): dead after attn
    u16*   VTb     = (u16*)(ws + 192 * MB);   // [192,256M): dead after attn
    u16*   attnb   = (u16*)(ws + 256 * MB);   // [256,320M): dead after o-proj
    u16*   Oob     = (u16*)(ws + 320 * MB);   // [320,384M): dead after ln1_chain
    u16*   Cb      = (u16*)(ws + 64 * MB);    // [64,256M): (N,1536); live to ln2
    u16*   deltasB = (u16*)(ws + 256 * MB);   // over attnb; dead after state_chain
    u16*   statesb = (u16*)(ws + 320 * MB);   // over Oob; dead after seq gemm
    u16*   ffn_inb = (u16*)(ws + 0);          // over xb
    u16*   hb      = (u16*)(ws + 256 * MB);   // over deltasB: 64M chunk, reused x4
    u16*   Fob     = (u16*)(ws + 320 * MB);   // over statesb
    u16*   WSq  = (u16*)(ws + 448 * MB);      // 1536x512  = 1.5M
    u16*   WSo  = (u16*)(ws + 450 * MB);      // 512x512   = 0.5M
    u16*   WSgd = (u16*)(ws + 451 * MB);      // 1024x1536 = 3M
    u16*   WSs  = (u16*)(ws + 455 * MB);      // 512x512
    u16*   WSf1 = (u16*)(ws + 456 * MB);      // 2048x512  = 2M
    u16*   WSf2 = (u16*)(ws + 458 * MB);      // 512x2048  = 2M
    float* qkvb = (float*)(ws + 460 * MB);    // 1536 f32
    float* gdb  = (float*)(ws + 461 * MB);    // 1024 f32

    float* tabc   = out + SLOT;               // tables dead after attn
    float* tabs   = tabc + TT * 64;
    float* fstate = out + SLOT;               // written by state_chain (after attn)

    const size_t NE = (size_t)NROWS * DD;

    // 0. tables, casts, weight prep (all independent)
    rope_table_kernel<<<(TT * 64 + 255) / 256, 256, 0, stream>>>(tabc, tabs);
    cast_f2b_kernel<<<(unsigned)((NE / 4 + 255) / 256), 256, 0, stream>>>(x, xb, NE / 4);
    bias_build_kernel<<<2, 256, 0, stream>>>(q_b, k_b, v_b, gate_b, delta_b, qkvb, gdb);
    auto wt = [&](const float* W, u16* WT, int K, int M, int rmul, int roff) {
        wtrans_kernel<<<dim3(M / 32, K / 32), dim3(32, 8), 0, stream>>>(W, WT, K, M, rmul, roff);
    };
    wt(q_w, WSq, DD, DD, 1, 0);
    wt(k_w, WSq + (size_t)512 * DD, DD, DD, 1, 0);
    wt(v_w, WSq + (size_t)1024 * DD, DD, DD, 1, 0);
    wt(o_w, WSo, DD, DD, 1, 0);
    wt(gate_w,  WSgd, 3 * DD, DD, 2, 0);
    wt(delta_w, WSgd, 3 * DD, DD, 2, 1);
    wt(seq_w, WSs, DD, DD, 1, 0);
    wt(ffn_w1, WSf1, DD, FFD, 1, 0);
    wt(ffn_w2, WSf2, FFD, DD, 1, 0);

    // 1. fused QKV GEMM (M=1536, 128^2 dbuf): q|k -> QKb, v -> VTb tiles
    gemm_bf16<7><<<dim3(12, 512), 256, 0, stream>>>(
        xb, WSq, qkvb, QKb, 1024, nullptr, VTb, DD, 1536);

    // 2. fused MFMA attention (RoPE inline) -> attnb
    attn_mfma_kernel<<<dim3(HH, BB), 256, 0, stream>>>(QKb, VTb, attnb, tabc, tabs);

    // 3. o-proj -> Oob bf16 (256^2 quadrant)
    gemm256<4><<<dim3(2, 256), 512, 0, stream>>>(
        attnb, WSo, o_b, Oob, DD, nullptr, DD, DD);

    // 4. ln1_chain: x1/conv/ema -> Cb (x1 lives only in Cb[:,0:512])
    ln1_chain_kernel<<<BB, 512, 0, stream>>>(xb, Oob, ln1_g, ln1_b, local_w, local_b, Cb);

    // 5. fused gate/delta GEMM (M=1024 interleaved) + act -> deltasB bf16
    gemm256<6><<<dim3(4, 256), 512, 0, stream>>>(
        Cb, WSgd, gdb, deltasB, DD, nullptr, 3 * DD, 1024);

    // 6. state_chain -> statesb bf16; LN4 -> fstate
    state_chain_kernel<<<BB, 512, 0, stream>>>(
        deltasB, seqst, dn_g, dn_b, ln3_g, ln3_b, ln4_g, ln4_b, statesb, fstate);

    // 7. ffn_in = x1(Cb bf16, stride 1536) + 0.3*(states@seq_w+b) -> ffn_inb
    gemm256<2><<<dim3(2, 256), 512, 0, stream>>>(
        statesb, WSs, seq_b, ffn_inb, DD, Cb, DD, 1536);

    // 8. FFN in 4 row-chunks (hb 64MB stays L3-hot, region reused)
    {
        const int CH = 16384;
        for (int c = 0; c < 4; ++c) {
            const u16* Ain = ffn_inb + (size_t)c * CH * DD;
            u16* Cchunk    = Fob     + (size_t)c * CH * DD;
            gemm256<3><<<dim3(8, CH / 256), 512, 0, stream>>>(
                Ain, WSf1, ffn_b1, hb, FFD, nullptr, DD, FFD);
            gemm256<4><<<dim3(2, CH / 256), 512, 0, stream>>>(
                hb, WSf2, ffn_b2, Cchunk, DD, nullptr, FFD, DD);
        }
    }

    // 9. out = LN2(x1(Cb) + ffn_out) -> d_out
    ln2_kernel<<<NROWS, 256, 0, stream>>>(Cb, Fob, ln2_g, ln2_b, out);
}

// Round 12
// 1621.323 us; speedup vs baseline: 1.1273x; 1.0965x over previous
//
#include <hip/hip_runtime.h>
#include <cstddef>
#include <cstdint>

#define BB   512
#define TT   128
#define DD   512
#define HH   4
#define HDIM 128
#define FFD  2048
#define NROWS (BB * TT)                 // 65536 rows
#define SLOT ((size_t)NROWS * DD)       // 33554432 floats = 128 MiB

typedef unsigned short u16;
typedef __bf16 bf16x8 __attribute__((ext_vector_type(8)));
typedef float  f32x4  __attribute__((ext_vector_type(4)));

__device__ __forceinline__ u16 f2b(float x) {
    union { float f; unsigned u; } v; v.f = x;
    unsigned r = v.u + 0x7FFFu + ((v.u >> 16) & 1u);
    return (u16)(r >> 16);
}
__device__ __forceinline__ float b2f(u16 u) {
    union { unsigned u; float f; } v; v.u = (unsigned)u << 16; return v.f;
}
__device__ __forceinline__ float fast_gelu(float v) {
    float t = v * (0.7978845608028654f + 0.0356774081f * v * v);
    float e = __expf(2.f * t);
    float th = 1.f - 2.f / (e + 1.f);          // tanh(t)
    return 0.5f * v * (1.f + th);
}
__device__ __forceinline__ void glds16(const void* g, void* l) {
    __builtin_amdgcn_global_load_lds(
        (const __attribute__((address_space(1))) void*)g,
        (__attribute__((address_space(3))) void*)l, 16, 0, 0);
}

#define BAR() asm volatile("s_barrier" ::: "memory")
#define MM(ACC, AV, BV) \
    ACC = __builtin_amdgcn_mfma_f32_16x16x32_bf16(AV, BV, ACC, 0, 0, 0)

// ============ 256x256 quadrant-phase bf16 GEMM (R6-best) ====================
// MODE 2: bf16 out = addsrc_bf16[r*M+c] + 0.3*C. MODE 3: bf16 gelu(C).
// MODE 4: bf16 C. MODE 6: gate/delta interleave -> sigmoid*tanh @ c>>1.
template<int MODE>
__global__ __launch_bounds__(512, 2)
void gemm256(const u16* __restrict__ A, const u16* __restrict__ BT,
             const float* __restrict__ bias, void* __restrict__ Cout, int ldc,
             const u16* __restrict__ addsrc, int K, int M)
{
    __shared__ u16 S[65536];   // 128 KiB
    const int tid = threadIdx.x;
    const int gx  = gridDim.x;               // M/256
    const int nwg = gx * gridDim.y;
    int orig = blockIdx.y * gx + blockIdx.x;
    orig = (orig & 7) * (nwg >> 3) + (orig >> 3);   // XCD swizzle (nwg%8==0)
    const int row0 = (orig / gx) * 256;
    const int col0 = (orig % gx) * 256;

    const int lane = tid & 63;
    const int wid  = tid >> 6;
    const int wm   = wid >> 2;       // row half (0/1)
    const int wn   = wid & 3;        // col quarter (0..3)
    const int fr   = lane & 15;
    const int kq   = lane >> 4;      // 0..3

    // staging: phys chunk c -> logical l = c ^ (((c>>5)&1)<<1)  (16B chunks)
    const int c0 = wid * 128 + lane;
    const int c1 = c0 + 64;
    const int l0 = c0 ^ (((c0 >> 5) & 1) << 1);
    const int l1 = c1 ^ (((c1 >> 5) & 1) << 1);
    const int sr0 = l0 >> 2, sk0 = (l0 & 3) * 8;
    const int sr1 = l1 >> 2, sk1 = (l1 & 3) * 8;
    const u16* ApG = A  + (size_t)row0 * K;
    const u16* BpG = BT + (size_t)col0 * K;

    auto stA = [&](int kt, int kh) {
        char* slot = (char*)S + ((((kt & 1) << 1) + kh) << 14);
        const u16* g = ApG + kt * 64 + kh * 32;
        glds16(g + (size_t)sr0 * K + sk0, slot + c0 * 16);
        glds16(g + (size_t)sr1 * K + sk1, slot + c1 * 16);
    };
    auto stB = [&](int kt, int kh) {
        char* slot = (char*)S + 65536 + ((((kt & 1) << 1) + kh) << 14);
        const u16* g = BpG + kt * 64 + kh * 32;
        glds16(g + (size_t)sr0 * K + sk0, slot + c0 * 16);
        glds16(g + (size_t)sr1 * K + sk1, slot + c1 * 16);
    };
    auto rdA = [&](int p, int kh, int m) -> bf16x8 {
        const int row = wm * 128 + m * 16 + fr;
        const int L = (row * 64 + kq * 16) ^ (((row >> 3) & 1) << 5);
        return *(const bf16x8*)((char*)S + (((p << 1) + kh) << 14) + L);
    };
    auto rdB = [&](int p, int kh, int n) -> bf16x8 {
        const int col = wn * 64 + n * 16 + fr;
        const int L = (col * 64 + kq * 16) ^ (((col >> 3) & 1) << 5);
        return *(const bf16x8*)((char*)S + 65536 + (((p << 1) + kh) << 14) + L);
    };

    f32x4 acc[8][4];
#pragma unroll
    for (int m = 0; m < 8; ++m)
#pragma unroll
        for (int n = 0; n < 4; ++n) acc[m][n] = (f32x4){0.f, 0.f, 0.f, 0.f};

    const int NKT = K >> 6;

    // prologue: tile0 (4 slabs) + B(1,0), B(1,1), A(1,0)
    stA(0, 0); stA(0, 1); stB(0, 0); stB(0, 1);
    stB(1, 0); stB(1, 1); stA(1, 0);
    asm volatile("s_waitcnt vmcnt(6)" ::: "memory");
    BAR();

    for (int kt = 0; kt < NKT; ++kt) {
        const int p = kt & 1;
        const bool s1 = (kt + 1 < NKT);
        const bool s2 = (kt + 2 < NKT);
        bf16x8 a0, a1, a2, a3, a4, a5, a6, a7;         // A frags [kh][m-quarter]
        bf16x8 b00, b01, b02, b03, b10, b11, b12, b13; // B frags [kh][n]

        // ---- ph1: (m0-3, n0-1); stage A(kt+1,1) -> slot p^1 ----
        if (s1) stA(kt + 1, 1);
        a0 = rdA(p, 0, 0); a1 = rdA(p, 0, 1); a2 = rdA(p, 0, 2); a3 = rdA(p, 0, 3);
        a4 = rdA(p, 1, 0); a5 = rdA(p, 1, 1); a6 = rdA(p, 1, 2); a7 = rdA(p, 1, 3);
        b00 = rdB(p, 0, 0); b01 = rdB(p, 0, 1);
        b10 = rdB(p, 1, 0); b11 = rdB(p, 1, 1);
        BAR();
        __builtin_amdgcn_s_setprio(1);
        MM(acc[0][0], a0, b00); MM(acc[0][1], a0, b01);
        MM(acc[1][0], a1, b00); MM(acc[1][1], a1, b01);
        MM(acc[2][0], a2, b00); MM(acc[2][1], a2, b01);
        MM(acc[3][0], a3, b00); MM(acc[3][1], a3, b01);
        MM(acc[0][0], a4, b10); MM(acc[0][1], a4, b11);
        MM(acc[1][0], a5, b10); MM(acc[1][1], a5, b11);
        MM(acc[2][0], a6, b10); MM(acc[2][1], a6, b11);
        MM(acc[3][0], a7, b10); MM(acc[3][1], a7, b11);
        __builtin_amdgcn_s_setprio(0);
        BAR();

        // ---- ph2: (m0-3, n2-3); A held; read B n2-3 ----
        b02 = rdB(p, 0, 2); b03 = rdB(p, 0, 3);
        b12 = rdB(p, 1, 2); b13 = rdB(p, 1, 3);
        BAR();
        __builtin_amdgcn_s_setprio(1);
        MM(acc[0][2], a0, b02); MM(acc[0][3], a0, b03);
        MM(acc[1][2], a1, b02); MM(acc[1][3], a1, b03);
        MM(acc[2][2], a2, b02); MM(acc[2][3], a2, b03);
        MM(acc[3][2], a3, b02); MM(acc[3][3], a3, b03);
        MM(acc[0][2], a4, b12); MM(acc[0][3], a4, b13);
        MM(acc[1][2], a5, b12); MM(acc[1][3], a5, b13);
        MM(acc[2][2], a6, b12); MM(acc[2][3], a6, b13);
        MM(acc[3][2], a7, b12); MM(acc[3][3], a7, b13);
        __builtin_amdgcn_s_setprio(0);
        BAR();

        // ---- ph3: (m4-7, n0-1); stage B(kt+2,0) ----
        if (s2) stB(kt + 2, 0);
        a0 = rdA(p, 0, 4); a1 = rdA(p, 0, 5); a2 = rdA(p, 0, 6); a3 = rdA(p, 0, 7);
        a4 = rdA(p, 1, 4); a5 = rdA(p, 1, 5); a6 = rdA(p, 1, 6); a7 = rdA(p, 1, 7);
        BAR();
        __builtin_amdgcn_s_setprio(1);
        MM(acc[4][0], a0, b00); MM(acc[4][1], a0, b01);
        MM(acc[5][0], a1, b00); MM(acc[5][1], a1, b01);
        MM(acc[6][0], a2, b00); MM(acc[6][1], a2, b01);
        MM(acc[7][0], a3, b00); MM(acc[7][1], a3, b01);
        MM(acc[4][0], a4, b10); MM(acc[4][1], a4, b11);
        MM(acc[5][0], a5, b10); MM(acc[5][1], a5, b11);
        MM(acc[6][0], a6, b10); MM(acc[6][1], a6, b11);
        MM(acc[7][0], a7, b10); MM(acc[7][1], a7, b11);
        __builtin_amdgcn_s_setprio(0);
        BAR();

        // ---- ph4: (m4-7, n2-3); stage B(kt+2,1)+A(kt+2,0) ----
        if (s2) { stB(kt + 2, 1); stA(kt + 2, 0); }
        __builtin_amdgcn_s_setprio(1);
        MM(acc[4][2], a0, b02); MM(acc[4][3], a0, b03);
        MM(acc[5][2], a1, b02); MM(acc[5][3], a1, b03);
        MM(acc[6][2], a2, b02); MM(acc[6][3], a2, b03);
        MM(acc[7][2], a3, b02); MM(acc[7][3], a3, b03);
        MM(acc[4][2], a4, b12); MM(acc[4][3], a4, b13);
        MM(acc[5][2], a5, b12); MM(acc[5][3], a5, b13);
        MM(acc[6][2], a6, b12); MM(acc[6][3], a6, b13);
        MM(acc[7][2], a7, b12); MM(acc[7][3], a7, b13);
        __builtin_amdgcn_s_setprio(0);
        if (s2)      asm volatile("s_waitcnt vmcnt(6)" ::: "memory");
        else if (s1) asm volatile("s_waitcnt vmcnt(0)" ::: "memory");
        if (s1) BAR();
    }

    // ---- epilogue ----
#pragma unroll
    for (int m = 0; m < 8; ++m) {
#pragma unroll
        for (int jj = 0; jj < 4; ++jj) {
            const int r = row0 + wm * 128 + m * 16 + kq * 4 + jj;
#pragma unroll
            for (int n = 0; n < 4; ++n) {
                const int c = col0 + wn * 64 + n * 16 + fr;
                float v = acc[m][n][jj] + bias[c];
                if constexpr (MODE == 2) {
                    float xs = b2f(addsrc[(size_t)r * M + c]);
                    ((u16*)Cout)[(size_t)r * ldc + c] = f2b(xs + 0.3f * v);
                } else if constexpr (MODE == 3) {
                    ((u16*)Cout)[(size_t)r * ldc + c] = f2b(fast_gelu(v));
                } else if constexpr (MODE == 6) {
                    float pth = __shfl_xor(v, 1);
                    if ((fr & 1) == 0) {
                        float sg = 1.f / (1.f + __expf(-v));
                        float e  = __expf(2.f * pth);
                        float th = 1.f - 2.f / (e + 1.f);
                        ((u16*)Cout)[(size_t)r * ldc + (c >> 1)] = f2b(sg * th);
                    }
                } else {  // MODE 4
                    ((u16*)Cout)[(size_t)r * ldc + c] = f2b(v);
                }
            }
        }
    }
}

// ---------------- 128x128 bf16 GEMM (QKV only, MODE 7, dbuf) ---------------
template<int MODE>
__global__ __launch_bounds__(256)
void gemm_bf16(const u16* __restrict__ A, const u16* __restrict__ BT,
               const float* __restrict__ bias, void* __restrict__ Cout, int ldc,
               const float* __restrict__ addsrc, void* __restrict__ aux,
               int K, int M)
{
    __shared__ u16 smem[16384];
    const int tid = threadIdx.x;
    const int gx  = gridDim.x;
    const int nwg = gx * gridDim.y;
    int orig = blockIdx.y * gx + blockIdx.x;
    if ((nwg & 7) == 0) orig = (orig & 7) * (nwg >> 3) + (orig >> 3);
    const int row0 = (orig / gx) * 128;
    const int col0 = (orig % gx) * 128;

    const int lane = tid & 63;
    const int w    = tid >> 6;
    const int wr   = (w >> 1) * 64;
    const int wc   = (w & 1) * 64;
    const int fr   = lane & 15;
    const int kg   = (lane >> 4) * 8;

    f32x4 acc[4][4];
#pragma unroll
    for (int m = 0; m < 4; ++m)
#pragma unroll
        for (int n = 0; n < 4; ++n) acc[m][n] = (f32x4){0.f, 0.f, 0.f, 0.f};

    const int srow = tid >> 2;
    const int skb  = (tid & 3) * 8;
    const u16* Ag = A  + (size_t)(row0 + srow) * K + skb;
    const u16* Bg = BT + (size_t)(col0 + srow) * K + skb;
    const int soff = srow * 32 + skb;

    auto stage = [&](int kt, int buf) {
        const int ko = kt * 32;
        u16* as = smem + buf * 8192 + soff;
        u16* bs = smem + buf * 8192 + 4096 + soff;
        glds16(Ag + ko,                  as);
        glds16(Ag + (size_t)64 * K + ko, as + 2048);
        glds16(Bg + ko,                  bs);
        glds16(Bg + (size_t)64 * K + ko, bs + 2048);
    };

    const int nk = K >> 5;
    stage(0, 0);
    for (int k = 0; k < nk; ++k) {
        if (k + 1 < nk) {
            stage(k + 1, (k + 1) & 1);
            asm volatile("s_waitcnt vmcnt(4)" ::: "memory");
        } else {
            asm volatile("s_waitcnt vmcnt(0)" ::: "memory");
        }
        __syncthreads();
        const u16* As = smem + (k & 1) * 8192;
        const u16* Bs = As + 4096;
        bf16x8 af[4], bfr[4];
#pragma unroll
        for (int m = 0; m < 4; ++m)
            af[m] = *reinterpret_cast<const bf16x8*>(&As[(wr + m * 16 + fr) * 32 + kg]);
#pragma unroll
        for (int n = 0; n < 4; ++n)
            bfr[n] = *reinterpret_cast<const bf16x8*>(&Bs[(wc + n * 16 + fr) * 32 + kg]);
#pragma unroll
        for (int m = 0; m < 4; ++m)
#pragma unroll
            for (int n = 0; n < 4; ++n)
                acc[m][n] = __builtin_amdgcn_mfma_f32_16x16x32_bf16(af[m], bfr[n], acc[m][n], 0, 0, 0);
        __syncthreads();
    }

    if constexpr (MODE == 7) {
        if (col0 >= 1024) {
            // V^T swizzled tile: Ct[dc][t] rows of 256B, byte ^= ((dc&7)<<4)
#pragma unroll
            for (int m = 0; m < 4; ++m)
#pragma unroll
                for (int j = 0; j < 4; ++j) {
                    const int tl = wr + m * 16 + (lane >> 4) * 4 + j;
#pragma unroll
                    for (int n = 0; n < 4; ++n) {
                        const int dc = wc + n * 16 + fr;
                        float v = acc[m][n][j] + bias[col0 + dc];
                        *(u16*)((char*)smem + dc * 256 + ((tl * 2) ^ ((dc & 7) << 4))) = f2b(v);
                    }
                }
            __syncthreads();
            u16* dst = (u16*)aux + ((size_t)((row0 >> 7) * 4 + ((col0 - 1024) >> 7)) << 14);
#pragma unroll
            for (int i = 0; i < 8; ++i)
                *(uint4*)(dst + (size_t)(i * 256 + tid) * 8) =
                    *(const uint4*)((char*)smem + (size_t)(i * 256 + tid) * 16);
        } else {
#pragma unroll
            for (int m = 0; m < 4; ++m)
#pragma unroll
                for (int j = 0; j < 4; ++j) {
                    const int r = row0 + wr + m * 16 + (lane >> 4) * 4 + j;
#pragma unroll
                    for (int n = 0; n < 4; ++n) {
                        const int c = col0 + wc + n * 16 + fr;
                        ((u16*)Cout)[(size_t)r * 1024 + c] = f2b(acc[m][n][j] + bias[c]);
                    }
                }
        }
    }
    (void)ldc; (void)addsrc;
}

// ------- weight transpose+cast: W (K,M) f32 -> WT rows (m*rmul+roff) -------
__global__ __launch_bounds__(256)
void wtrans_kernel(const float* __restrict__ W, u16* __restrict__ WT, int K, int M,
                   int rmul, int roff)
{
    __shared__ float t[32][33];
    const int m0 = blockIdx.x * 32;
    const int k0 = blockIdx.y * 32;
    const int tx = threadIdx.x;
    const int ty = threadIdx.y;
#pragma unroll
    for (int i = 0; i < 4; ++i) {
        int k = ty * 4 + i;
        t[k][tx] = W[(size_t)(k0 + k) * M + m0 + tx];
    }
    __syncthreads();
#pragma unroll
    for (int i = 0; i < 4; ++i) {
        int m = ty * 4 + i;
        WT[(size_t)((m0 + m) * rmul + roff) * K + k0 + tx] = f2b(t[tx][m]);
    }
}

__global__ void cast_f2b_kernel(const float* __restrict__ in, u16* __restrict__ out, size_t n4)
{
    size_t i = (size_t)blockIdx.x * blockDim.x + threadIdx.x;
    if (i >= n4) return;
    float4 v = reinterpret_cast<const float4*>(in)[i];
    union { u16 u[4]; uint2 d; } p;
    p.u[0] = f2b(v.x); p.u[1] = f2b(v.y); p.u[2] = f2b(v.z); p.u[3] = f2b(v.w);
    reinterpret_cast<uint2*>(out)[i] = p.d;
}

__global__ void rope_table_kernel(float* __restrict__ tabc, float* __restrict__ tabs)
{
    int idx = blockIdx.x * blockDim.x + threadIdx.x;
    if (idx >= TT * 64) return;
    int t = idx >> 6, j = idx & 63;
    float invf = expf(-(float)j * (9.210340371976184f / 64.f));
    float ang  = (float)t * invf;
    tabc[idx] = cosf(ang);
    tabs[idx] = sinf(ang);
}

__global__ void bias_build_kernel(const float* qb, const float* kb, const float* vb,
                                  const float* gb, const float* db,
                                  float* qkvb, float* gdb)
{
    int i = blockIdx.x * blockDim.x + threadIdx.x;
    if (i >= 512) return;
    qkvb[i] = qb[i]; qkvb[512 + i] = kb[i]; qkvb[1024 + i] = vb[i];
    gdb[2 * i] = gb[i]; gdb[2 * i + 1] = db[i];
}

// ---------------- MFMA attention: one block per (b,h), RoPE inline ---------
__global__ __launch_bounds__(256)
void attn_mfma_kernel(const u16* __restrict__ QKg, const u16* __restrict__ VTg,
                      u16* __restrict__ Og,
                      const float* __restrict__ tabc, const float* __restrict__ tabs)
{
    __shared__ u16 SA[128 * 128];   // Q -> P
    __shared__ u16 SB[128 * 128];   // K -> V^T
    const int h = blockIdx.x, b = blockIdx.y;
    const int tid  = threadIdx.x;
    const int lane = tid & 63;
    const int w    = tid >> 6;
    const int fr   = lane & 15;
    const int kq   = lane >> 4;
    const size_t baseq = ((size_t)(b * TT)) * 1024 + (size_t)h * HDIM;
    const size_t baseo = ((size_t)(b * TT)) * DD + (size_t)h * HDIM;

    {
        const int tg = tid >> 4;
        const int dg = tid & 15;
        const int j0 = (dg & 7) * 8;
        const bool hi = (dg & 8) != 0;
        for (int r = 0; r < 8; ++r) {
            const int t = r * 16 + tg;
            uint4 qv = *(const uint4*)(QKg + baseq + (size_t)t * 1024 + dg * 8);
            uint4 kv = *(const uint4*)(QKg + baseq + 512 + (size_t)t * 1024 + dg * 8);
            unsigned qa[4] = {qv.x, qv.y, qv.z, qv.w};
            unsigned ka[4] = {kv.x, kv.y, kv.z, kv.w};
            unsigned qb[4], kb[4];
#pragma unroll
            for (int i = 0; i < 4; ++i) {
                qb[i] = __shfl_xor((int)qa[i], 8);
                kb[i] = __shfl_xor((int)ka[i], 8);
            }
            const float* cp = tabc + t * 64 + j0;
            const float* sp = tabs + t * 64 + j0;
            u16 oq[8], ok[8];
#pragma unroll
            for (int e = 0; e < 8; ++e) {
                float fq = b2f((u16)(qa[e >> 1] >> ((e & 1) * 16)));
                float gq = b2f((u16)(qb[e >> 1] >> ((e & 1) * 16)));
                float fk = b2f((u16)(ka[e >> 1] >> ((e & 1) * 16)));
                float gk = b2f((u16)(kb[e >> 1] >> ((e & 1) * 16)));
                float c = cp[e], s = sp[e];
                oq[e] = f2b(hi ? fq * c + gq * s : fq * c - gq * s);
                ok[e] = f2b(hi ? fk * c + gk * s : fk * c - gk * s);
            }
            const int cb = (dg * 16) ^ ((t & 7) << 4);
            *(uint4*)((char*)SA + t * 256 + cb) = *(const uint4*)oq;
            *(uint4*)((char*)SB + t * 256 + cb) = *(const uint4*)ok;
        }
    }
    __syncthreads();

    f32x4 acc[2][8];
#pragma unroll
    for (int m = 0; m < 2; ++m)
#pragma unroll
        for (int n = 0; n < 8; ++n) acc[m][n] = (f32x4){0.f, 0.f, 0.f, 0.f};

    for (int k0 = 0; k0 < 128; k0 += 32) {
        const int cb = (k0 + kq * 8) * 2;
        bf16x8 af[2];
#pragma unroll
        for (int m = 0; m < 2; ++m) {
            const int row = w * 32 + m * 16 + fr;
            af[m] = *(const bf16x8*)((char*)SA + row * 256 + (cb ^ ((row & 7) << 4)));
        }
#pragma unroll
        for (int n = 0; n < 8; ++n) {
            const int row = n * 16 + fr;
            bf16x8 bf = *(const bf16x8*)((char*)SB + row * 256 + (cb ^ ((row & 7) << 4)));
            acc[0][n] = __builtin_amdgcn_mfma_f32_16x16x32_bf16(af[0], bf, acc[0][n], 0, 0, 0);
            acc[1][n] = __builtin_amdgcn_mfma_f32_16x16x32_bf16(af[1], bf, acc[1][n], 0, 0, 0);
        }
    }
    __syncthreads();

    {
        const u16* vsrc = VTg + ((size_t)(b * HH + h) << 14);
#pragma unroll
        for (int i = 0; i < 8; ++i)
            glds16(vsrc + (size_t)(i * 256 + tid) * 8,
                   SB + (size_t)(i * 256 + tid) * 8);
    }

    const float SC = 0.08838834764831845f;
#pragma unroll
    for (int m = 0; m < 2; ++m) {
#pragma unroll
        for (int j = 0; j < 4; ++j) {
            const int t = w * 32 + m * 16 + kq * 4 + j;
            float mx = -3.0e38f;
#pragma unroll
            for (int n = 0; n < 8; ++n) {
                const int s = n * 16 + fr;
                float v = acc[m][n][j];
                v = (s <= t) ? v * SC : -3.0e38f;
                acc[m][n][j] = v;
                mx = fmaxf(mx, v);
            }
            mx = fmaxf(mx, __shfl_xor(mx, 1));
            mx = fmaxf(mx, __shfl_xor(mx, 2));
            mx = fmaxf(mx, __shfl_xor(mx, 4));
            mx = fmaxf(mx, __shfl_xor(mx, 8));
            float sum = 0.f;
#pragma unroll
            for (int n = 0; n < 8; ++n) {
                float e = __expf(acc[m][n][j] - mx);
                acc[m][n][j] = e; sum += e;
            }
            sum += __shfl_xor(sum, 1); sum += __shfl_xor(sum, 2);
            sum += __shfl_xor(sum, 4); sum += __shfl_xor(sum, 8);
            const float inv = 1.f / sum;
#pragma unroll
            for (int n = 0; n < 8; ++n) {
                const int s = n * 16 + fr;
                *(u16*)((char*)SA + t * 256 + ((s * 2) ^ ((t & 7) << 4))) =
                    f2b(acc[m][n][j] * inv);
            }
        }
    }
    __syncthreads();

    f32x4 oa[2][8];
#pragma unroll
    for (int m = 0; m < 2; ++m)
#pragma unroll
        for (int n = 0; n < 8; ++n) oa[m][n] = (f32x4){0.f, 0.f, 0.f, 0.f};

    for (int k0 = 0; k0 < 128; k0 += 32) {
        const int cb = (k0 + kq * 8) * 2;
        bf16x8 pa[2];
#pragma unroll
        for (int m = 0; m < 2; ++m) {
            const int row = w * 32 + m * 16 + fr;
            pa[m] = *(const bf16x8*)((char*)SA + row * 256 + (cb ^ ((row & 7) << 4)));
        }
#pragma unroll
        for (int n = 0; n < 8; ++n) {
            const int row = n * 16 + fr;
            bf16x8 vb = *(const bf16x8*)((char*)SB + row * 256 + (cb ^ ((row & 7) << 4)));
            oa[0][n] = __builtin_amdgcn_mfma_f32_16x16x32_bf16(pa[0], vb, oa[0][n], 0, 0, 0);
            oa[1][n] = __builtin_amdgcn_mfma_f32_16x16x32_bf16(pa[1], vb, oa[1][n], 0, 0, 0);
        }
    }

#pragma unroll
    for (int m = 0; m < 2; ++m)
#pragma unroll
        for (int j = 0; j < 4; ++j) {
            const int t = w * 32 + m * 16 + kq * 4 + j;
            u16* orow = Og + baseo + (size_t)t * DD;
#pragma unroll
            for (int n = 0; n < 8; ++n)
                orow[n * 16 + fr] = f2b(oa[m][n][j]);
        }
}

// ---------------- block reduce over 512 threads (sum, sumsq) ---------------
__device__ __forceinline__ float2 blk_red512(float v, float (*red)[2], int tid)
{
    float s = v, ss = v * v;
#pragma unroll
    for (int off = 1; off < 64; off <<= 1) {
        s  += __shfl_xor(s, off);
        ss += __shfl_xor(ss, off);
    }
    if ((tid & 63) == 0) { red[tid >> 6][0] = s; red[tid >> 6][1] = ss; }
    __syncthreads();
    float S = 0.f, SS = 0.f;
#pragma unroll
    for (int w = 0; w < 8; ++w) { S += red[w][0]; SS += red[w][1]; }
    return make_float2(S, SS);
}

// ------- ln1_chain: per-batch serial LN1 + local conv + EMA (bf16 in) ------
__global__ __launch_bounds__(512)
void ln1_chain_kernel(const u16* __restrict__ xb, const u16* __restrict__ oo,
                      const float* __restrict__ g, const float* __restrict__ bb,
                      const float* __restrict__ lw, const float* __restrict__ lb,
                      u16* __restrict__ Cb)
{
    __shared__ float red[2][8][2];
    const int b = blockIdx.x, d = threadIdx.x;
    const float g_ = g[d], b_ = bb[d];
    const float w0 = lw[d * 4 + 0], w1 = lw[d * 4 + 1],
                w2 = lw[d * 4 + 2], w3 = lw[d * 4 + 3];
    const float lb_ = lb[d];
    const size_t rb = (size_t)b * TT;
    float h1 = 0.f, h2 = 0.f, h3 = 0.f, ema = 0.f;
    float v = b2f(xb[(rb + 0) * DD + d]) + b2f(oo[(rb + 0) * DD + d]);
    for (int t = 0; t < TT; ++t) {
        const int tn = (t < TT - 1) ? t + 1 : t;
        float vn = b2f(xb[(rb + tn) * DD + d]) + b2f(oo[(rb + tn) * DD + d]);
        float2 r = blk_red512(v, red[t & 1], d);
        float mu  = r.x * (1.f / DD);
        float var = r.y * (1.f / DD) - mu * mu;
        float x1v = (v - mu) * rsqrtf(var + 1e-5f) * g_ + b_;
        const size_t row = rb + t;
        u16* crow = Cb + row * 1536;
        crow[d] = f2b(x1v);
        crow[512 + d]  = f2b(lb_ + w3 * x1v + w2 * h1 + w1 * h2 + w0 * h3);
        ema = 0.9f * ema + 0.1f * x1v;
        crow[1024 + d] = f2b(ema);
        h3 = h2; h2 = h1; h1 = x1v;
        v = vn;
    }
}

// ------- state_chain: per-batch serial LN(dn)+cumsum+LN3 (+LN4 at t=127) ---
__global__ __launch_bounds__(512)
void state_chain_kernel(const u16* __restrict__ deltasB, const float* __restrict__ seqst,
                        const float* __restrict__ dng, const float* __restrict__ dnb,
                        const float* __restrict__ g3, const float* __restrict__ b3,
                        const float* __restrict__ g4, const float* __restrict__ b4,
                        u16* __restrict__ statesb, float* __restrict__ fstate)
{
    __shared__ float red[2][8][2];
    const int b = blockIdx.x, d = threadIdx.x;
    const float gd_ = dng[d], bd_ = dnb[d], g3_ = g3[d], b3_ = b3[d];
    const float seq = seqst[(size_t)b * DD + d];
    const size_t rb = (size_t)b * TT;
    float cum = 0.f;
    float v = b2f(deltasB[(rb + 0) * DD + d]);
    for (int t = 0; t < TT; ++t) {
        const int tn = (t < TT - 1) ? t + 1 : t;
        float vn = b2f(deltasB[(rb + tn) * DD + d]);
        float2 r0 = blk_red512(v, red[0], d);
        float mu  = r0.x * (1.f / DD);
        float var = r0.y * (1.f / DD) - mu * mu;
        float nd  = (v - mu) * rsqrtf(var + 1e-5f) * gd_ + bd_;
        cum += nd;
        float sv = seq + cum * 0.25f;
        float2 r1 = blk_red512(sv, red[1], d);
        mu  = r1.x * (1.f / DD);
        var = r1.y * (1.f / DD) - mu * mu;
        float o = (sv - mu) * rsqrtf(var + 1e-5f) * g3_ + b3_;
        statesb[(rb + t) * DD + d] = f2b(o);
        if (t == TT - 1) {
            float2 r2 = blk_red512(o, red[0], d);
            float mu4  = r2.x * (1.f / DD);
            float var4 = r2.y * (1.f / DD) - mu4 * mu4;
            fstate[(size_t)b * DD + d] = (o - mu4) * rsqrtf(var4 + 1e-5f) * g4[d] + b4[d];
        }
        v = vn;
    }
}

// ------- final LN2: x1 from Cb (stride 1536, bf16) + Fob bf16 -> f32 out ---
__global__ __launch_bounds__(256)
void ln2_kernel(const u16* __restrict__ x1cb, const u16* __restrict__ fo,
                const float* __restrict__ g, const float* __restrict__ bb,
                float* __restrict__ out)
{
    const int row = blockIdx.x;
    const int tid = threadIdx.x;
    const u16* ap = x1cb + (size_t)row * 1536;
    const u16* bp = fo   + (size_t)row * DD;
    float v0 = b2f(ap[tid])       + b2f(bp[tid]);
    float v1 = b2f(ap[tid + 256]) + b2f(bp[tid + 256]);
    float s  = v0 + v1;
    float ss = v0 * v0 + v1 * v1;
#pragma unroll
    for (int off = 1; off < 64; off <<= 1) {
        s  += __shfl_xor(s, off);
        ss += __shfl_xor(ss, off);
    }
    __shared__ float sm1[4], sm2[4];
    const int wid = tid >> 6;
    if ((tid & 63) == 0) { sm1[wid] = s; sm2[wid] = ss; }
    __syncthreads();
    s  = sm1[0] + sm1[1] + sm1[2] + sm1[3];
    ss = sm2[0] + sm2[1] + sm2[2] + sm2[3];
    const float mu  = s * (1.f / DD);
    const float var = ss * (1.f / DD) - mu * mu;
    const float r   = rsqrtf(var + 1e-5f);
    float* op = out + (size_t)row * DD;
    op[tid]       = (v0 - mu) * r * g[tid]       + bb[tid];
    op[tid + 256] = (v1 - mu) * r * g[tid + 256] + bb[tid + 256];
}

// ---------------------------------------------------------------------------
extern "C" void kernel_launch(void* const* d_in, const int* in_sizes, int n_in,
                              void* d_out, int out_size, void* d_ws, size_t ws_size,
                              hipStream_t stream)
{
    const float* x       = (const float*)d_in[0];
    const float* seqst   = (const float*)d_in[1];
    const float* q_w     = (const float*)d_in[2];
    const float* q_b     = (const float*)d_in[3];
    const float* k_w     = (const float*)d_in[4];
    const float* k_b     = (const float*)d_in[5];
    const float* v_w     = (const float*)d_in[6];
    const float* v_b     = (const float*)d_in[7];
    const float* o_w     = (const float*)d_in[8];
    const float* o_b     = (const float*)d_in[9];
    const float* local_w = (const float*)d_in[10];
    const float* local_b = (const float*)d_in[11];
    const float* delta_w = (const float*)d_in[12];
    const float* delta_b = (const float*)d_in[13];
    const float* gate_w  = (const float*)d_in[14];
    const float* gate_b  = (const float*)d_in[15];
    const float* dn_g    = (const float*)d_in[16];
    const float* dn_b    = (const float*)d_in[17];
    const float* ln1_g   = (const float*)d_in[18];
    const float* ln1_b   = (const float*)d_in[19];
    const float* ln2_g   = (const float*)d_in[20];
    const float* ln2_b   = (const float*)d_in[21];
    const float* ln3_g   = (const float*)d_in[22];
    const float* ln3_b   = (const float*)d_in[23];
    const float* ln4_g   = (const float*)d_in[24];
    const float* ln4_b   = (const float*)d_in[25];
    const float* seq_w   = (const float*)d_in[26];
    const float* seq_b   = (const float*)d_in[27];
    const float* ffn_w1  = (const float*)d_in[28];
    const float* ffn_b1  = (const float*)d_in[29];
    const float* ffn_w2  = (const float*)d_in[30];
    const float* ffn_b2  = (const float*)d_in[31];
    (void)in_sizes; (void)n_in; (void)out_size; (void)ws_size;

    float* out = (float*)d_out;
    char*  ws  = (char*)d_ws;
    const size_t MB = (size_t)1 << 20;

    // ---- region map (byte offsets in d_ws) ----
    u16*   xb      = (u16*)(ws + 0);          // [0,64M): live until ln1_chain
    u16*   QKb     = (u16*)(ws + 64 * MB);    // [64,192M): dead after attn
    u16*   VTb     = (u16*)(ws + 192 * MB);   // [192,256M): dead after attn
    u16*   attnb   = (u16*)(ws + 256 * MB);   // [256,320M): dead after o-proj
    u16*   Oob     = (u16*)(ws + 320 * MB);   // [320,384M): dead after ln1_chain
    u16*   Cb      = (u16*)(ws + 64 * MB);    // [64,256M): (N,1536); live to ln2
    u16*   deltasB = (u16*)(ws + 256 * MB);   // over attnb; dead after state_chain
    u16*   statesb = (u16*)(ws + 320 * MB);   // over Oob; dead after seq gemm
    u16*   ffn_inb = (u16*)(ws + 0);          // over xb
    u16*   hb      = (u16*)(ws + 256 * MB);   // [256,384M): 128M chunk, reused x2
    u16*   Fob     = (u16*)(ws + 384 * MB);   // [384,448M)
    u16*   WSq  = (u16*)(ws + 448 * MB);      // 1536x512  = 1.5M
    u16*   WSo  = (u16*)(ws + 450 * MB);      // 512x512   = 0.5M
    u16*   WSgd = (u16*)(ws + 451 * MB);      // 1024x1536 = 3M
    u16*   WSs  = (u16*)(ws + 455 * MB);      // 512x512
    u16*   WSf1 = (u16*)(ws + 456 * MB);      // 2048x512  = 2M
    u16*   WSf2 = (u16*)(ws + 458 * MB);      // 512x2048  = 2M
    float* qkvb = (float*)(ws + 460 * MB);    // 1536 f32
    float* gdb  = (float*)(ws + 461 * MB);    // 1024 f32

    float* tabc   = out + SLOT;               // tables dead after attn
    float* tabs   = tabc + TT * 64;
    float* fstate = out + SLOT;               // written by state_chain (after attn)

    const size_t NE = (size_t)NROWS * DD;

    // 0. tables, casts, weight prep (all independent)
    rope_table_kernel<<<(TT * 64 + 255) / 256, 256, 0, stream>>>(tabc, tabs);
    cast_f2b_kernel<<<(unsigned)((NE / 4 + 255) / 256), 256, 0, stream>>>(x, xb, NE / 4);
    bias_build_kernel<<<2, 256, 0, stream>>>(q_b, k_b, v_b, gate_b, delta_b, qkvb, gdb);
    auto wt = [&](const float* W, u16* WT, int K, int M, int rmul, int roff) {
        wtrans_kernel<<<dim3(M / 32, K / 32), dim3(32, 8), 0, stream>>>(W, WT, K, M, rmul, roff);
    };
    wt(q_w, WSq, DD, DD, 1, 0);
    wt(k_w, WSq + (size_t)512 * DD, DD, DD, 1, 0);
    wt(v_w, WSq + (size_t)1024 * DD, DD, DD, 1, 0);
    wt(o_w, WSo, DD, DD, 1, 0);
    wt(gate_w,  WSgd, 3 * DD, DD, 2, 0);
    wt(delta_w, WSgd, 3 * DD, DD, 2, 1);
    wt(seq_w, WSs, DD, DD, 1, 0);
    wt(ffn_w1, WSf1, DD, FFD, 1, 0);
    wt(ffn_w2, WSf2, FFD, DD, 1, 0);

    // 1. fused QKV GEMM (M=1536, 128^2 dbuf): q|k -> QKb, v -> VTb tiles
    gemm_bf16<7><<<dim3(12, 512), 256, 0, stream>>>(
        xb, WSq, qkvb, QKb, 1024, nullptr, VTb, DD, 1536);

    // 2. fused MFMA attention (RoPE inline) -> attnb
    attn_mfma_kernel<<<dim3(HH, BB), 256, 0, stream>>>(QKb, VTb, attnb, tabc, tabs);

    // 3. o-proj -> Oob bf16 (256^2 quadrant)
    gemm256<4><<<dim3(2, 256), 512, 0, stream>>>(
        attnb, WSo, o_b, Oob, DD, nullptr, DD, DD);

    // 4. ln1_chain: x1/conv/ema -> Cb (x1 lives only in Cb[:,0:512])
    ln1_chain_kernel<<<BB, 512, 0, stream>>>(xb, Oob, ln1_g, ln1_b, local_w, local_b, Cb);

    // 5. fused gate/delta GEMM (M=1024 interleaved) + act -> deltasB bf16
    gemm256<6><<<dim3(4, 256), 512, 0, stream>>>(
        Cb, WSgd, gdb, deltasB, DD, nullptr, 3 * DD, 1024);

    // 6. state_chain -> statesb bf16; LN4 -> fstate
    state_chain_kernel<<<BB, 512, 0, stream>>>(
        deltasB, seqst, dn_g, dn_b, ln3_g, ln3_b, ln4_g, ln4_b, statesb, fstate);

    // 7. ffn_in = x1(Cb bf16, stride 1536) + 0.3*(states@seq_w+b) -> ffn_inb
    gemm256<2><<<dim3(2, 256), 512, 0, stream>>>(
        statesb, WSs, seq_b, ffn_inb, DD, Cb, DD, 1536);

    // 8. FFN in 2 row-chunks of 32768 (hb chunk 128MB L3-resident; FFN2
    //    grid = 256 blocks = 1/CU, full machine)
    {
        const int CH = 32768;
        for (int c = 0; c < 2; ++c) {
            const u16* Ain = ffn_inb + (size_t)c * CH * DD;
            u16* Cchunk    = Fob     + (size_t)c * CH * DD;
            gemm256<3><<<dim3(8, CH / 256), 512, 0, stream>>>(
                Ain, WSf1, ffn_b1, hb, FFD, nullptr, DD, FFD);
            gemm256<4><<<dim3(2, CH / 256), 512, 0, stream>>>(
                hb, WSf2, ffn_b2, Cchunk, DD, nullptr, FFD, DD);
        }
    }

    // 9. out = LN2(x1(Cb) + ffn_out) -> d_out
    ln2_kernel<<<NROWS, 256, 0, stream>>>(Cb, Fob, ln2_g, ln2_b, out);
}